// Round 1
// baseline (4216.977 us; speedup 1.0000x reference)
//
#include <hip/hip_runtime.h>
#include <stdint.h>
#include <stddef.h>

// ---------------------------------------------------------------------------
// JAX threefry2x32 (Skein rotation constants, 20 rounds, 5 key injections).
// Matches jax/_src/prng.py exactly.
// ---------------------------------------------------------------------------
__host__ __device__ __forceinline__ uint32_t rotl32(uint32_t v, uint32_t r) {
  return (v << r) | (v >> (32u - r));
}

__host__ __device__ __forceinline__ void tf2x32(uint32_t k0, uint32_t k1,
                                                uint32_t x0, uint32_t x1,
                                                uint32_t& o0, uint32_t& o1) {
  uint32_t ks2 = k0 ^ k1 ^ 0x1BD11BDAu;
  x0 += k0; x1 += k1;
  x0 += x1; x1 = rotl32(x1, 13); x1 ^= x0;
  x0 += x1; x1 = rotl32(x1, 15); x1 ^= x0;
  x0 += x1; x1 = rotl32(x1, 26); x1 ^= x0;
  x0 += x1; x1 = rotl32(x1, 6);  x1 ^= x0;
  x0 += k1; x1 += ks2 + 1u;
  x0 += x1; x1 = rotl32(x1, 17); x1 ^= x0;
  x0 += x1; x1 = rotl32(x1, 29); x1 ^= x0;
  x0 += x1; x1 = rotl32(x1, 16); x1 ^= x0;
  x0 += x1; x1 = rotl32(x1, 24); x1 ^= x0;
  x0 += ks2; x1 += k0 + 2u;
  x0 += x1; x1 = rotl32(x1, 13); x1 ^= x0;
  x0 += x1; x1 = rotl32(x1, 15); x1 ^= x0;
  x0 += x1; x1 = rotl32(x1, 26); x1 ^= x0;
  x0 += x1; x1 = rotl32(x1, 6);  x1 ^= x0;
  x0 += k0; x1 += k1 + 3u;
  x0 += x1; x1 = rotl32(x1, 17); x1 ^= x0;
  x0 += x1; x1 = rotl32(x1, 29); x1 ^= x0;
  x0 += x1; x1 = rotl32(x1, 16); x1 ^= x0;
  x0 += x1; x1 = rotl32(x1, 24); x1 ^= x0;
  x0 += k1; x1 += ks2 + 4u;
  x0 += x1; x1 = rotl32(x1, 13); x1 ^= x0;
  x0 += x1; x1 = rotl32(x1, 15); x1 ^= x0;
  x0 += x1; x1 = rotl32(x1, 26); x1 ^= x0;
  x0 += x1; x1 = rotl32(x1, 6);  x1 ^= x0;
  x0 += ks2; x1 += k0 + 5u;
  o0 = x0; o1 = x1;
}

// Partitionable-mode random bits for flat index i (< 2^32): bits = o0^o1 of
// threefry(key, (0, i)); keep (uniform<0.5) <=> top bit of bits == 0.
__device__ __forceinline__ bool tf_keep(uint32_t k0, uint32_t k1, uint32_t idx) {
  uint32_t o0, o1;
  tf2x32(k0, k1, 0u, idx, o0, o1);
  return ((o0 ^ o1) >> 31) == 0u;
}

// ---------------------------------------------------------------------------
// Kernels
// ---------------------------------------------------------------------------
__global__ __launch_bounds__(256) void init_deg(uint32_t* __restrict__ deg, int n) {
  int i = blockIdx.x * 256 + threadIdx.x;
  if (i < n) deg[i] = 1u;  // self-loop
}

__global__ __launch_bounds__(256) void count_deg(const int* __restrict__ dst,
                                                 uint32_t* __restrict__ deg, int E) {
  int i = blockIdx.x * 256 + threadIdx.x;
  if (i < E) atomicAdd(&deg[dst[i]], 1u);
}

__global__ __launch_bounds__(256) void make_dinv(const uint32_t* __restrict__ deg,
                                                 float* __restrict__ dinv, int n) {
  int i = blockIdx.x * 256 + threadIdx.x;
  if (i < n) dinv[i] = 1.0f / sqrtf((float)deg[i]);
}

__global__ __launch_bounds__(256) void zero_k(float4* __restrict__ p, int n4) {
  int t = blockIdx.x * 256 + threadIdx.x;
  if (t < n4) p[t] = make_float4(0.f, 0.f, 0.f, 0.f);
}

// h = X[n,64] @ W[64,32], epilogue scale by dinv[row]. 8 rows x 32 cols / block.
__global__ __launch_bounds__(256) void gemm_n64_k32(
    const float* __restrict__ X, const float* __restrict__ W,
    const float* __restrict__ dinv, float* __restrict__ out, int n) {
  __shared__ float Ws[64 * 32];
  __shared__ float Xs[8 * 64];
  for (int i = threadIdx.x; i < 64 * 32; i += 256) Ws[i] = W[i];
  int row0 = blockIdx.x * 8;
  for (int i = threadIdx.x; i < 8 * 64; i += 256) {
    int r = row0 + (i >> 6);
    Xs[i] = (r < n) ? X[(size_t)r * 64 + (i & 63)] : 0.f;
  }
  __syncthreads();
  int r = threadIdx.x >> 5;
  int row = row0 + r;
  int col = threadIdx.x & 31;
  if (row >= n) return;
  float acc = 0.f;
#pragma unroll
  for (int k = 0; k < 64; ++k) acc = fmaf(Xs[r * 64 + k], Ws[k * 32 + col], acc);
  out[(size_t)row * 32 + col] = acc * dinv[row];
}

// out = dropout_k(celu(X[n,32] @ W[32,64] + b)). 4 rows x 64 cols / block.
__global__ __launch_bounds__(256) void gemm_k32_n64_act(
    const float* __restrict__ X, const float* __restrict__ W,
    const float* __restrict__ bias, float* __restrict__ out,
    uint32_t k0, uint32_t k1, int n) {
  __shared__ float Ws[32 * 64];
  __shared__ float Xs[4 * 32];
  for (int i = threadIdx.x; i < 32 * 64; i += 256) Ws[i] = W[i];
  int row0 = blockIdx.x * 4;
  for (int i = threadIdx.x; i < 4 * 32; i += 256) {
    int r = row0 + (i >> 5);
    Xs[i] = (r < n) ? X[(size_t)r * 32 + (i & 31)] : 0.f;
  }
  __syncthreads();
  int r = threadIdx.x >> 6;
  int row = row0 + r;
  int col = threadIdx.x & 63;
  if (row >= n) return;
  float acc = bias[col];
#pragma unroll
  for (int k = 0; k < 32; ++k) acc = fmaf(Xs[r * 32 + k], Ws[k * 64 + col], acc);
  float v = acc > 0.f ? acc : expm1f(acc);
  v = tf_keep(k0, k1, (uint32_t)(row * 64 + col)) ? v * 2.f : 0.f;
  out[(size_t)row * 64 + col] = v;
}

// agg[dst] += hs[src] over 32 dims; one thread per (edge, 4-dim chunk).
__global__ __launch_bounds__(256) void scatter32(
    const float* __restrict__ hs, const int* __restrict__ src,
    const int* __restrict__ dst, float* __restrict__ agg, int E) {
  int t = blockIdx.x * 256 + threadIdx.x;
  int e = t >> 3;
  if (e >= E) return;
  int c = (t & 7) << 2;
  int s = src[e], d = dst[e];
  const float4 v = *(const float4*)(hs + ((size_t)s << 5) + c);
  float* p = agg + ((size_t)d << 5) + c;
  unsafeAtomicAdd(p + 0, v.x);
  unsafeAtomicAdd(p + 1, v.y);
  unsafeAtomicAdd(p + 2, v.z);
  unsafeAtomicAdd(p + 3, v.w);
}

// out = f(dinv[j]*(agg + self)); mode 0: none; 1: +bias,celu; 2: +bias,celu,dropout
__global__ __launch_bounds__(256) void finalize32(
    const float* __restrict__ agg, const float* __restrict__ selfv,
    const float* __restrict__ dinv, const float* __restrict__ bias,
    float* __restrict__ out, int n, int mode, uint32_t k0, uint32_t k1) {
  int t = blockIdx.x * 256 + threadIdx.x;
  if (t >= n * 32) return;
  int j = t >> 5;
  float v = dinv[j] * (agg[t] + selfv[t]);
  if (mode >= 1) {
    v += bias[t & 31];
    v = v > 0.f ? v : expm1f(v);
  }
  if (mode == 2) {
    v = tf_keep(k0, k1, (uint32_t)t) ? v * 2.f : 0.f;
  }
  out[t] = v;
}

__global__ __launch_bounds__(256) void pre_scale(
    const float* __restrict__ in, const float* __restrict__ dinv,
    float* __restrict__ out, int n) {
  int t = blockIdx.x * 256 + threadIdx.x;
  if (t < n * 32) out[t] = in[t] * dinv[t >> 5];
}

// ---------------------------------------------------------------------------
extern "C" void kernel_launch(void* const* d_in, const int* in_sizes, int n_in,
                              void* d_out, int out_size, void* d_ws, size_t ws_size,
                              hipStream_t stream) {
  const float* x  = (const float*)d_in[0];
  const int*   ei = (const int*)d_in[1];
  const float* W1 = (const float*)d_in[2];
  const float* b1 = (const float*)d_in[3];
  const float* W2 = (const float*)d_in[4];
  const float* b2 = (const float*)d_in[5];
  const float* W3 = (const float*)d_in[6];
  const float* b3 = (const float*)d_in[7];
  float* out = (float*)d_out;

  const int n = in_sizes[0] / 64;
  const int E = in_sizes[1] / 2;
  const int* src = ei;
  const int* dst = ei + E;

  char* ws = (char*)d_ws;
  size_t off = 0;
  auto alloc = [&](size_t bytes) {
    void* p = ws + off;
    off = (off + bytes + 255) & ~(size_t)255;
    return p;
  };
  float*    A    = (float*)alloc((size_t)n * 32 * 4);   // hs / scaled features
  float*    B    = (float*)alloc((size_t)n * 32 * 4);   // agg / intermediate
  float*    C    = (float*)alloc((size_t)n * 64 * 4);   // layer-2 output (64-d)
  uint32_t* deg  = (uint32_t*)alloc((size_t)n * 4);
  float*    dinv = (float*)alloc((size_t)n * 4);
  (void)ws_size; (void)n_in; (void)out_size;

  // Dropout keys: key(42) = (0,42); partitionable fold-like split:
  // k_i = threefry(key, (0, i)).
  uint32_t k1a, k1b, k2a, k2b;
  tf2x32(0u, 42u, 0u, 0u, k1a, k1b);
  tf2x32(0u, 42u, 0u, 1u, k2a, k2b);

  const int nv   = n * 32;           // 3.2M elems in 32-d buffers
  const int gN   = (n + 255) / 256;
  const int gE   = (E + 255) / 256;
  const int gV   = (nv + 255) / 256;
  const int gZ   = (nv / 4 + 255) / 256;
  const int gS   = (E * 8 + 255) / 256;
  const int gG1  = (n + 7) / 8;
  const int gG2  = (n + 3) / 4;
  dim3 blk(256);

  // degrees + normalization
  init_deg<<<gN, blk, 0, stream>>>(deg, n);
  count_deg<<<gE, blk, 0, stream>>>(dst, deg, E);
  make_dinv<<<gN, blk, 0, stream>>>(deg, dinv, n);

  // ---- layer 1: h1 = x@W1 (64->32), aggregate, +b1, celu, dropout(k1) ----
  gemm_n64_k32<<<gG1, blk, 0, stream>>>(x, W1, dinv, A, n);
  zero_k<<<gZ, blk, 0, stream>>>((float4*)B, nv / 4);
  scatter32<<<gS, blk, 0, stream>>>(A, src, dst, B, E);
  finalize32<<<gV, blk, 0, stream>>>(B, A, dinv, b1, B, n, 2, k1a, k1b);

  // ---- layer 2: aggregate hd1 (32-d) first, then @W2 (+b2, celu, dropout k2)
  pre_scale<<<gV, blk, 0, stream>>>(B, dinv, A, n);
  zero_k<<<gZ, blk, 0, stream>>>((float4*)B, nv / 4);
  scatter32<<<gS, blk, 0, stream>>>(A, src, dst, B, E);
  finalize32<<<gV, blk, 0, stream>>>(B, A, dinv, nullptr, B, n, 0, 0u, 0u);
  gemm_k32_n64_act<<<gG2, blk, 0, stream>>>(B, W2, b2, C, k2a, k2b, n);

  // ---- layer 3: h3 = hd2@W3 (64->32), aggregate, +b3, celu -> out ----
  gemm_n64_k32<<<gG1, blk, 0, stream>>>(C, W3, dinv, A, n);
  zero_k<<<gZ, blk, 0, stream>>>((float4*)B, nv / 4);
  scatter32<<<gS, blk, 0, stream>>>(A, src, dst, B, E);
  finalize32<<<gV, blk, 0, stream>>>(B, A, dinv, b3, out, n, 1, 0u, 0u);
}

// Round 2
// 866.742 us; speedup vs baseline: 4.8653x; 4.8653x over previous
//
#include <hip/hip_runtime.h>
#include <stdint.h>
#include <stddef.h>

// ---------------------------------------------------------------------------
// JAX threefry2x32 (partitionable mode — verified round 1, absmax 2.4e-4).
// ---------------------------------------------------------------------------
__host__ __device__ __forceinline__ uint32_t rotl32(uint32_t v, uint32_t r) {
  return (v << r) | (v >> (32u - r));
}

__host__ __device__ __forceinline__ void tf2x32(uint32_t k0, uint32_t k1,
                                                uint32_t x0, uint32_t x1,
                                                uint32_t& o0, uint32_t& o1) {
  uint32_t ks2 = k0 ^ k1 ^ 0x1BD11BDAu;
  x0 += k0; x1 += k1;
  x0 += x1; x1 = rotl32(x1, 13); x1 ^= x0;
  x0 += x1; x1 = rotl32(x1, 15); x1 ^= x0;
  x0 += x1; x1 = rotl32(x1, 26); x1 ^= x0;
  x0 += x1; x1 = rotl32(x1, 6);  x1 ^= x0;
  x0 += k1; x1 += ks2 + 1u;
  x0 += x1; x1 = rotl32(x1, 17); x1 ^= x0;
  x0 += x1; x1 = rotl32(x1, 29); x1 ^= x0;
  x0 += x1; x1 = rotl32(x1, 16); x1 ^= x0;
  x0 += x1; x1 = rotl32(x1, 24); x1 ^= x0;
  x0 += ks2; x1 += k0 + 2u;
  x0 += x1; x1 = rotl32(x1, 13); x1 ^= x0;
  x0 += x1; x1 = rotl32(x1, 15); x1 ^= x0;
  x0 += x1; x1 = rotl32(x1, 26); x1 ^= x0;
  x0 += x1; x1 = rotl32(x1, 6);  x1 ^= x0;
  x0 += k0; x1 += k1 + 3u;
  x0 += x1; x1 = rotl32(x1, 17); x1 ^= x0;
  x0 += x1; x1 = rotl32(x1, 29); x1 ^= x0;
  x0 += x1; x1 = rotl32(x1, 16); x1 ^= x0;
  x0 += x1; x1 = rotl32(x1, 24); x1 ^= x0;
  x0 += k1; x1 += ks2 + 4u;
  x0 += x1; x1 = rotl32(x1, 13); x1 ^= x0;
  x0 += x1; x1 = rotl32(x1, 15); x1 ^= x0;
  x0 += x1; x1 = rotl32(x1, 26); x1 ^= x0;
  x0 += x1; x1 = rotl32(x1, 6);  x1 ^= x0;
  x0 += ks2; x1 += k0 + 5u;
  o0 = x0; o1 = x1;
}

__device__ __forceinline__ bool tf_keep(uint32_t k0, uint32_t k1, uint32_t idx) {
  uint32_t o0, o1;
  tf2x32(k0, k1, 0u, idx, o0, o1);
  return ((o0 ^ o1) >> 31) == 0u;
}

// ---------------------------------------------------------------------------
// CSR build: histogram -> exclusive scan -> placement (counting sort by dst)
// ---------------------------------------------------------------------------
__global__ __launch_bounds__(256) void zero_cnt(uint32_t* __restrict__ cnt, int n) {
  int i = blockIdx.x * 256 + threadIdx.x;
  if (i < n) cnt[i] = 0u;
}

__global__ __launch_bounds__(256) void hist(const int* __restrict__ dst,
                                            uint32_t* __restrict__ cnt, int E) {
  int i = blockIdx.x * 256 + threadIdx.x;
  if (i < E) atomicAdd(&cnt[dst[i]], 1u);
}

// dinv[i] = 1/sqrt(cnt[i] + 1)  (self-loop folded in)
__global__ __launch_bounds__(256) void make_dinv(const uint32_t* __restrict__ cnt,
                                                 float* __restrict__ dinv, int n) {
  int i = blockIdx.x * 256 + threadIdx.x;
  if (i < n) dinv[i] = 1.0f / sqrtf((float)(cnt[i] + 1u));
}

__global__ __launch_bounds__(256) void scan1(const uint32_t* __restrict__ cnt,
                                             uint32_t* __restrict__ rowp,
                                             uint32_t* __restrict__ bsum, int n) {
  __shared__ uint32_t s[256];
  int i = blockIdx.x * 256 + threadIdx.x;
  uint32_t v = (i < n) ? cnt[i] : 0u;
  s[threadIdx.x] = v;
  __syncthreads();
  for (int off = 1; off < 256; off <<= 1) {
    uint32_t t = (threadIdx.x >= off) ? s[threadIdx.x - off] : 0u;
    __syncthreads();
    if (threadIdx.x >= off) s[threadIdx.x] += t;
    __syncthreads();
  }
  if (i < n) rowp[i] = s[threadIdx.x] - v;  // exclusive within block
  if (threadIdx.x == 255) bsum[blockIdx.x] = s[255];
}

__global__ __launch_bounds__(512) void scan2(uint32_t* __restrict__ bsum, int nb) {
  __shared__ uint32_t s[512];
  int i = threadIdx.x;
  uint32_t v = (i < nb) ? bsum[i] : 0u;
  s[i] = v;
  __syncthreads();
  for (int off = 1; off < 512; off <<= 1) {
    uint32_t t = (i >= off) ? s[i - off] : 0u;
    __syncthreads();
    if (i >= off) s[i] += t;
    __syncthreads();
  }
  if (i < nb) bsum[i] = s[i] - v;  // exclusive
}

// rowp[i] += bsum[i/256]; cur[i]=rowp[i]; rowp[n]=E
__global__ __launch_bounds__(256) void scan3(uint32_t* __restrict__ rowp,
                                             const uint32_t* __restrict__ bsum,
                                             uint32_t* __restrict__ cur, int n, int E) {
  int i = blockIdx.x * 256 + threadIdx.x;
  if (i < n) {
    uint32_t r = rowp[i] + bsum[i >> 8];
    rowp[i] = r;
    cur[i] = r;
  } else if (i == n) {
    rowp[n] = (uint32_t)E;
  }
}

__global__ __launch_bounds__(256) void place(const int* __restrict__ src,
                                             const int* __restrict__ dst,
                                             uint32_t* __restrict__ cur,
                                             uint32_t* __restrict__ esrc, int E) {
  int e = blockIdx.x * 256 + threadIdx.x;
  if (e < E) {
    uint32_t pos = atomicAdd(&cur[dst[e]], 1u);
    esrc[pos] = (uint32_t)src[e];
  }
}

// ---------------------------------------------------------------------------
// GEMMs (unchanged from round 1 — correct, off the critical path)
// ---------------------------------------------------------------------------
__global__ __launch_bounds__(256) void gemm_n64_k32(
    const float* __restrict__ X, const float* __restrict__ W,
    const float* __restrict__ dinv, float* __restrict__ out, int n) {
  __shared__ float Ws[64 * 32];
  __shared__ float Xs[8 * 64];
  for (int i = threadIdx.x; i < 64 * 32; i += 256) Ws[i] = W[i];
  int row0 = blockIdx.x * 8;
  for (int i = threadIdx.x; i < 8 * 64; i += 256) {
    int r = row0 + (i >> 6);
    Xs[i] = (r < n) ? X[(size_t)r * 64 + (i & 63)] : 0.f;
  }
  __syncthreads();
  int r = threadIdx.x >> 5;
  int row = row0 + r;
  int col = threadIdx.x & 31;
  if (row >= n) return;
  float acc = 0.f;
#pragma unroll
  for (int k = 0; k < 64; ++k) acc = fmaf(Xs[r * 64 + k], Ws[k * 32 + col], acc);
  out[(size_t)row * 32 + col] = acc * dinv[row];
}

__global__ __launch_bounds__(256) void gemm_k32_n64_act(
    const float* __restrict__ X, const float* __restrict__ W,
    const float* __restrict__ bias, float* __restrict__ out,
    uint32_t k0, uint32_t k1, int n) {
  __shared__ float Ws[32 * 64];
  __shared__ float Xs[4 * 32];
  for (int i = threadIdx.x; i < 32 * 64; i += 256) Ws[i] = W[i];
  int row0 = blockIdx.x * 4;
  for (int i = threadIdx.x; i < 4 * 32; i += 256) {
    int r = row0 + (i >> 5);
    Xs[i] = (r < n) ? X[(size_t)r * 32 + (i & 31)] : 0.f;
  }
  __syncthreads();
  int r = threadIdx.x >> 6;
  int row = row0 + r;
  int col = threadIdx.x & 63;
  if (row >= n) return;
  float acc = bias[col];
#pragma unroll
  for (int k = 0; k < 32; ++k) acc = fmaf(Xs[r * 32 + k], Ws[k * 64 + col], acc);
  float v = acc > 0.f ? acc : expm1f(acc);
  v = tf_keep(k0, k1, (uint32_t)(row * 64 + col)) ? v * 2.f : 0.f;
  out[(size_t)row * 64 + col] = v;
}

// ---------------------------------------------------------------------------
// Gather-reduce aggregation + fused epilogue.
// thread t: dst j = t>>5, dim c = t&31. acc = self + sum_{e in CSR[j]} hs[esrc[e]][c]
// mode 0: v = dinv[j]*acc                        (feeds GEMM of layer 2)
// mode 1: v = celu(dinv[j]*acc + b[c])           (final output, layer 3)
// mode 3: v = dinv[j]*dropout(celu(dinv[j]*acc + b[c]))  (layer 1 -> layer 2 gather)
// ---------------------------------------------------------------------------
__global__ __launch_bounds__(256) void gather_fin(
    const float* __restrict__ hs, const uint32_t* __restrict__ rowp,
    const uint32_t* __restrict__ esrc, const float* __restrict__ dinv,
    const float* __restrict__ bias, float* __restrict__ out,
    int n, int mode, uint32_t k0, uint32_t k1) {
  int t = blockIdx.x * 256 + threadIdx.x;
  if (t >= n * 32) return;
  int j = t >> 5;
  int c = t & 31;
  float acc = hs[t];  // self-loop term (already dinv[src]-scaled)
  uint32_t e = rowp[j], e1 = rowp[j + 1];
  // 2-way unrolled edge loop: both row loads issued before either add
  for (; e + 2 <= e1; e += 2) {
    uint32_t s0 = esrc[e];
    uint32_t s1 = esrc[e + 1];
    float v0 = hs[((size_t)s0 << 5) + c];
    float v1 = hs[((size_t)s1 << 5) + c];
    acc += v0;
    acc += v1;
  }
  if (e < e1) acc += hs[((size_t)esrc[e] << 5) + c];
  float dj = dinv[j];
  float v = dj * acc;
  if (mode == 1) {
    v += bias[c];
    v = v > 0.f ? v : expm1f(v);
  } else if (mode == 3) {
    v += bias[c];
    v = v > 0.f ? v : expm1f(v);
    v = tf_keep(k0, k1, (uint32_t)t) ? v * 2.f : 0.f;
    v *= dj;  // pre-scale for next layer's gather
  }
  out[t] = v;
}

// ---------------------------------------------------------------------------
extern "C" void kernel_launch(void* const* d_in, const int* in_sizes, int n_in,
                              void* d_out, int out_size, void* d_ws, size_t ws_size,
                              hipStream_t stream) {
  const float* x  = (const float*)d_in[0];
  const int*   ei = (const int*)d_in[1];
  const float* W1 = (const float*)d_in[2];
  const float* b1 = (const float*)d_in[3];
  const float* W2 = (const float*)d_in[4];
  const float* b2 = (const float*)d_in[5];
  const float* W3 = (const float*)d_in[6];
  const float* b3 = (const float*)d_in[7];
  float* out = (float*)d_out;

  const int n = in_sizes[0] / 64;
  const int E = in_sizes[1] / 2;
  const int* src = ei;
  const int* dst = ei + E;

  char* ws = (char*)d_ws;
  size_t off = 0;
  auto alloc = [&](size_t bytes) {
    void* p = ws + off;
    off = (off + bytes + 255) & ~(size_t)255;
    return p;
  };
  float*    A    = (float*)alloc((size_t)n * 32 * 4);
  float*    B    = (float*)alloc((size_t)n * 32 * 4);
  float*    C    = (float*)alloc((size_t)n * 64 * 4);
  uint32_t* cnt  = (uint32_t*)alloc((size_t)n * 4);      // hist, then cursor
  float*    dinv = (float*)alloc((size_t)n * 4);
  uint32_t* rowp = (uint32_t*)alloc((size_t)(n + 1) * 4);
  uint32_t* esrc = (uint32_t*)alloc((size_t)E * 4);
  uint32_t* bsum = (uint32_t*)alloc(4096);
  (void)ws_size; (void)n_in; (void)out_size;

  uint32_t k1a, k1b, k2a, k2b;
  tf2x32(0u, 42u, 0u, 0u, k1a, k1b);
  tf2x32(0u, 42u, 0u, 1u, k2a, k2b);

  const int nv  = n * 32;
  const int nb  = (n + 255) / 256;          // 391 blocks for n=100k
  const int gN  = nb;
  const int gN1 = (n + 1 + 255) / 256;
  const int gE  = (E + 255) / 256;
  const int gV  = (nv + 255) / 256;
  const int gG1 = (n + 7) / 8;
  const int gG2 = (n + 3) / 4;
  dim3 blk(256);

  // ---- CSR build (once; reused by all three layers) ----
  zero_cnt<<<gN, blk, 0, stream>>>(cnt, n);
  hist<<<gE, blk, 0, stream>>>(dst, cnt, E);
  make_dinv<<<gN, blk, 0, stream>>>(cnt, dinv, n);
  scan1<<<gN, blk, 0, stream>>>(cnt, rowp, bsum, n);
  scan2<<<1, dim3(512), 0, stream>>>(bsum, nb);
  scan3<<<gN1, blk, 0, stream>>>(rowp, bsum, cnt, n, E);   // cnt becomes cursor
  place<<<gE, blk, 0, stream>>>(src, dst, cnt, esrc, E);

  // ---- layer 1: A = dinv*(x@W1); gather+bias+celu+dropout(k1)+dinv -> B ----
  gemm_n64_k32<<<gG1, blk, 0, stream>>>(x, W1, dinv, A, n);
  gather_fin<<<gV, blk, 0, stream>>>(A, rowp, esrc, dinv, b1, B, n, 3, k1a, k1b);

  // ---- layer 2: gather(B) -> A; A@W2+b2, celu, dropout(k2) -> C ----
  gather_fin<<<gV, blk, 0, stream>>>(B, rowp, esrc, dinv, nullptr, A, n, 0, 0u, 0u);
  gemm_k32_n64_act<<<gG2, blk, 0, stream>>>(A, W2, b2, C, k2a, k2b, n);

  // ---- layer 3: A = dinv*(C@W3); gather+bias+celu -> out ----
  gemm_n64_k32<<<gG1, blk, 0, stream>>>(C, W3, dinv, A, n);
  gather_fin<<<gV, blk, 0, stream>>>(A, rowp, esrc, dinv, b3, out, n, 1, 0u, 0u);
}

// Round 3
// 469.986 us; speedup vs baseline: 8.9726x; 1.8442x over previous
//
#include <hip/hip_runtime.h>
#include <stdint.h>
#include <stddef.h>

// ---------------------------------------------------------------------------
// JAX threefry2x32 (partitionable mode — verified: absmax 2.4e-4).
// ---------------------------------------------------------------------------
__host__ __device__ __forceinline__ uint32_t rotl32(uint32_t v, uint32_t r) {
  return (v << r) | (v >> (32u - r));
}

__host__ __device__ __forceinline__ void tf2x32(uint32_t k0, uint32_t k1,
                                                uint32_t x0, uint32_t x1,
                                                uint32_t& o0, uint32_t& o1) {
  uint32_t ks2 = k0 ^ k1 ^ 0x1BD11BDAu;
  x0 += k0; x1 += k1;
  x0 += x1; x1 = rotl32(x1, 13); x1 ^= x0;
  x0 += x1; x1 = rotl32(x1, 15); x1 ^= x0;
  x0 += x1; x1 = rotl32(x1, 26); x1 ^= x0;
  x0 += x1; x1 = rotl32(x1, 6);  x1 ^= x0;
  x0 += k1; x1 += ks2 + 1u;
  x0 += x1; x1 = rotl32(x1, 17); x1 ^= x0;
  x0 += x1; x1 = rotl32(x1, 29); x1 ^= x0;
  x0 += x1; x1 = rotl32(x1, 16); x1 ^= x0;
  x0 += x1; x1 = rotl32(x1, 24); x1 ^= x0;
  x0 += ks2; x1 += k0 + 2u;
  x0 += x1; x1 = rotl32(x1, 13); x1 ^= x0;
  x0 += x1; x1 = rotl32(x1, 15); x1 ^= x0;
  x0 += x1; x1 = rotl32(x1, 26); x1 ^= x0;
  x0 += x1; x1 = rotl32(x1, 6);  x1 ^= x0;
  x0 += k0; x1 += k1 + 3u;
  x0 += x1; x1 = rotl32(x1, 17); x1 ^= x0;
  x0 += x1; x1 = rotl32(x1, 29); x1 ^= x0;
  x0 += x1; x1 = rotl32(x1, 16); x1 ^= x0;
  x0 += x1; x1 = rotl32(x1, 24); x1 ^= x0;
  x0 += k1; x1 += ks2 + 4u;
  x0 += x1; x1 = rotl32(x1, 13); x1 ^= x0;
  x0 += x1; x1 = rotl32(x1, 15); x1 ^= x0;
  x0 += x1; x1 = rotl32(x1, 26); x1 ^= x0;
  x0 += x1; x1 = rotl32(x1, 6);  x1 ^= x0;
  x0 += ks2; x1 += k0 + 5u;
  o0 = x0; o1 = x1;
}

__device__ __forceinline__ bool tf_keep(uint32_t k0, uint32_t k1, uint32_t idx) {
  uint32_t o0, o1;
  tf2x32(k0, k1, 0u, idx, o0, o1);
  return ((o0 ^ o1) >> 31) == 0u;
}

// ---------------------------------------------------------------------------
// Bucketed CSR build. Bucket b = dst>>8 (256 nodes/bucket, NB = ceil(n/256)).
// Packed staging entry: (dst&255)<<17 | src   (src < 2^17).
// ---------------------------------------------------------------------------
#define CHUNK 8192

__global__ __launch_bounds__(512) void zero512(uint32_t* __restrict__ p) {
  p[threadIdx.x] = 0u;
}

// per-bucket totals, LDS-aggregated
__global__ __launch_bounds__(256) void kbhist(const int* __restrict__ dst,
                                              uint32_t* __restrict__ gbcnt,
                                              int E, int NB) {
  __shared__ uint32_t lc[512];
  for (int i = threadIdx.x; i < NB; i += 256) lc[i] = 0u;
  __syncthreads();
  int base = blockIdx.x * CHUNK;
  int end = min(base + CHUNK, E);
  for (int i = base + threadIdx.x; i < end; i += 256)
    atomicAdd(&lc[((uint32_t)dst[i]) >> 8], 1u);
  __syncthreads();
  for (int i = threadIdx.x; i < NB; i += 256)
    if (lc[i]) atomicAdd(&gbcnt[i], lc[i]);
}

// exclusive scan of gbcnt -> bbase, gcur (NB <= 512, one block)
__global__ __launch_bounds__(512) void kbscan(const uint32_t* __restrict__ gbcnt,
                                              uint32_t* __restrict__ bbase,
                                              uint32_t* __restrict__ gcur, int NB) {
  __shared__ uint32_t s[512];
  int i = threadIdx.x;
  uint32_t v = (i < NB) ? gbcnt[i] : 0u;
  s[i] = v;
  __syncthreads();
  for (int off = 1; off < 512; off <<= 1) {
    uint32_t t = (i >= off) ? s[i - off] : 0u;
    __syncthreads();
    if (i >= off) s[i] += t;
    __syncthreads();
  }
  if (i < NB) {
    uint32_t e = s[i] - v;
    bbase[i] = e;
    gcur[i] = e;
  }
}

// bin edges into bucket-contiguous staging (two-phase LDS reservation)
__global__ __launch_bounds__(256) void kbin(const int* __restrict__ src,
                                            const int* __restrict__ dst,
                                            uint32_t* __restrict__ gcur,
                                            uint32_t* __restrict__ staging,
                                            int E, int NB) {
  __shared__ uint32_t lcnt[512];
  __shared__ uint32_t lbase[512];
  for (int i = threadIdx.x; i < NB; i += 256) lcnt[i] = 0u;
  __syncthreads();
  int base = blockIdx.x * CHUNK;
  int end = min(base + CHUNK, E);
  for (int i = base + threadIdx.x; i < end; i += 256)
    atomicAdd(&lcnt[((uint32_t)dst[i]) >> 8], 1u);
  __syncthreads();
  for (int i = threadIdx.x; i < NB; i += 256) {
    uint32_t c = lcnt[i];
    lbase[i] = c ? atomicAdd(&gcur[i], c) : 0u;
    lcnt[i] = 0u;
  }
  __syncthreads();
  for (int i = base + threadIdx.x; i < end; i += 256) {
    uint32_t d = (uint32_t)dst[i];
    uint32_t b = d >> 8;
    uint32_t off = atomicAdd(&lcnt[b], 1u);
    staging[lbase[b] + off] = ((d & 255u) << 17) | (uint32_t)src[i];
  }
}

// per-node counts from staging (one block per bucket, LDS counters)
__global__ __launch_bounds__(256) void kcount(const uint32_t* __restrict__ staging,
                                              const uint32_t* __restrict__ bbase,
                                              const uint32_t* __restrict__ gbcnt,
                                              uint32_t* __restrict__ cnt, int n) {
  __shared__ uint32_t lc[256];
  lc[threadIdx.x] = 0u;
  __syncthreads();
  int b = blockIdx.x;
  uint32_t s = bbase[b], c = gbcnt[b];
  for (uint32_t i = threadIdx.x; i < c; i += 256)
    atomicAdd(&lc[staging[s + i] >> 17], 1u);
  __syncthreads();
  int node = (b << 8) + threadIdx.x;
  if (node < n) cnt[node] = lc[threadIdx.x];
}

// dinv[i] = 1/sqrt(cnt[i] + 1)  (self-loop folded in)
__global__ __launch_bounds__(256) void make_dinv(const uint32_t* __restrict__ cnt,
                                                 float* __restrict__ dinv, int n) {
  int i = blockIdx.x * 256 + threadIdx.x;
  if (i < n) dinv[i] = 1.0f / sqrtf((float)(cnt[i] + 1u));
}

__global__ __launch_bounds__(256) void scan1(const uint32_t* __restrict__ cnt,
                                             uint32_t* __restrict__ rowp,
                                             uint32_t* __restrict__ bsum, int n) {
  __shared__ uint32_t s[256];
  int i = blockIdx.x * 256 + threadIdx.x;
  uint32_t v = (i < n) ? cnt[i] : 0u;
  s[threadIdx.x] = v;
  __syncthreads();
  for (int off = 1; off < 256; off <<= 1) {
    uint32_t t = (threadIdx.x >= off) ? s[threadIdx.x - off] : 0u;
    __syncthreads();
    if (threadIdx.x >= off) s[threadIdx.x] += t;
    __syncthreads();
  }
  if (i < n) rowp[i] = s[threadIdx.x] - v;
  if (threadIdx.x == 255) bsum[blockIdx.x] = s[255];
}

__global__ __launch_bounds__(512) void scan2(uint32_t* __restrict__ bsum, int nb) {
  __shared__ uint32_t s[512];
  int i = threadIdx.x;
  uint32_t v = (i < nb) ? bsum[i] : 0u;
  s[i] = v;
  __syncthreads();
  for (int off = 1; off < 512; off <<= 1) {
    uint32_t t = (i >= off) ? s[i - off] : 0u;
    __syncthreads();
    if (i >= off) s[i] += t;
    __syncthreads();
  }
  if (i < nb) bsum[i] = s[i] - v;
}

__global__ __launch_bounds__(256) void scan3(uint32_t* __restrict__ rowp,
                                             const uint32_t* __restrict__ bsum,
                                             int n, int E) {
  int i = blockIdx.x * 256 + threadIdx.x;
  if (i < n) rowp[i] += bsum[i >> 8];
  else if (i == n) rowp[n] = (uint32_t)E;
}

// fine placement (one block per bucket, LDS cursors; esrc writes XCD-local)
__global__ __launch_bounds__(256) void kplace(const uint32_t* __restrict__ staging,
                                              const uint32_t* __restrict__ bbase,
                                              const uint32_t* __restrict__ gbcnt,
                                              const uint32_t* __restrict__ rowp,
                                              uint32_t* __restrict__ esrc, int n) {
  __shared__ uint32_t lcur[256];
  int b = blockIdx.x;
  int node = (b << 8) + threadIdx.x;
  lcur[threadIdx.x] = (node < n) ? rowp[node] : 0u;
  __syncthreads();
  uint32_t s = bbase[b], c = gbcnt[b];
  for (uint32_t i = threadIdx.x; i < c; i += 256) {
    uint32_t p = staging[s + i];
    uint32_t pos = atomicAdd(&lcur[p >> 17], 1u);
    esrc[pos] = p & 0x1FFFFu;
  }
}

// ---------------------------------------------------------------------------
// GEMMs
// ---------------------------------------------------------------------------
__global__ __launch_bounds__(256) void gemm_n64_k32(
    const float* __restrict__ X, const float* __restrict__ W,
    const float* __restrict__ dinv, float* __restrict__ out, int n) {
  __shared__ float Ws[64 * 32];
  __shared__ float Xs[8 * 64];
  for (int i = threadIdx.x; i < 64 * 32; i += 256) Ws[i] = W[i];
  int row0 = blockIdx.x * 8;
  for (int i = threadIdx.x; i < 8 * 64; i += 256) {
    int r = row0 + (i >> 6);
    Xs[i] = (r < n) ? X[(size_t)r * 64 + (i & 63)] : 0.f;
  }
  __syncthreads();
  int r = threadIdx.x >> 5;
  int row = row0 + r;
  int col = threadIdx.x & 31;
  if (row >= n) return;
  float acc = 0.f;
#pragma unroll
  for (int k = 0; k < 64; ++k) acc = fmaf(Xs[r * 64 + k], Ws[k * 32 + col], acc);
  out[(size_t)row * 32 + col] = acc * dinv[row];
}

__global__ __launch_bounds__(256) void gemm_k32_n64_act(
    const float* __restrict__ X, const float* __restrict__ W,
    const float* __restrict__ bias, float* __restrict__ out,
    uint32_t k0, uint32_t k1, int n) {
  __shared__ float Ws[32 * 64];
  __shared__ float Xs[4 * 32];
  for (int i = threadIdx.x; i < 32 * 64; i += 256) Ws[i] = W[i];
  int row0 = blockIdx.x * 4;
  for (int i = threadIdx.x; i < 4 * 32; i += 256) {
    int r = row0 + (i >> 5);
    Xs[i] = (r < n) ? X[(size_t)r * 32 + (i & 31)] : 0.f;
  }
  __syncthreads();
  int r = threadIdx.x >> 6;
  int row = row0 + r;
  int col = threadIdx.x & 63;
  if (row >= n) return;
  float acc = bias[col];
#pragma unroll
  for (int k = 0; k < 32; ++k) acc = fmaf(Xs[r * 32 + k], Ws[k * 64 + col], acc);
  float v = acc > 0.f ? acc : expm1f(acc);
  v = tf_keep(k0, k1, (uint32_t)(row * 64 + col)) ? v * 2.f : 0.f;
  out[(size_t)row * 64 + col] = v;
}

// ---------------------------------------------------------------------------
// Gather-reduce aggregation + fused epilogue (4-way unrolled edge loop).
// ---------------------------------------------------------------------------
__global__ __launch_bounds__(256) void gather_fin(
    const float* __restrict__ hs, const uint32_t* __restrict__ rowp,
    const uint32_t* __restrict__ esrc, const float* __restrict__ dinv,
    const float* __restrict__ bias, float* __restrict__ out,
    int n, int mode, uint32_t k0, uint32_t k1) {
  int t = blockIdx.x * 256 + threadIdx.x;
  if (t >= n * 32) return;
  int j = t >> 5;
  int c = t & 31;
  float acc = hs[t];  // self-loop (already dinv[src]-scaled)
  uint32_t e = rowp[j], e1 = rowp[j + 1];
  for (; e + 4 <= e1; e += 4) {
    uint32_t s0 = esrc[e], s1 = esrc[e + 1], s2 = esrc[e + 2], s3 = esrc[e + 3];
    float v0 = hs[(s0 << 5) + c];
    float v1 = hs[(s1 << 5) + c];
    float v2 = hs[(s2 << 5) + c];
    float v3 = hs[(s3 << 5) + c];
    acc += (v0 + v1) + (v2 + v3);
  }
  for (; e < e1; ++e) acc += hs[(esrc[e] << 5) + c];
  float dj = dinv[j];
  float v = dj * acc;
  if (mode == 1) {
    v += bias[c];
    v = v > 0.f ? v : expm1f(v);
  } else if (mode == 3) {
    v += bias[c];
    v = v > 0.f ? v : expm1f(v);
    v = tf_keep(k0, k1, (uint32_t)t) ? v * 2.f : 0.f;
    v *= dj;
  }
  out[t] = v;
}

// ---------------------------------------------------------------------------
extern "C" void kernel_launch(void* const* d_in, const int* in_sizes, int n_in,
                              void* d_out, int out_size, void* d_ws, size_t ws_size,
                              hipStream_t stream) {
  const float* x  = (const float*)d_in[0];
  const int*   ei = (const int*)d_in[1];
  const float* W1 = (const float*)d_in[2];
  const float* b1 = (const float*)d_in[3];
  const float* W2 = (const float*)d_in[4];
  const float* b2 = (const float*)d_in[5];
  const float* W3 = (const float*)d_in[6];
  const float* b3 = (const float*)d_in[7];
  float* out = (float*)d_out;

  const int n = in_sizes[0] / 64;
  const int E = in_sizes[1] / 2;
  const int* src = ei;
  const int* dst = ei + E;

  char* ws = (char*)d_ws;
  size_t off = 0;
  auto alloc = [&](size_t bytes) {
    void* p = ws + off;
    off = (off + bytes + 255) & ~(size_t)255;
    return p;
  };
  float*    A     = (float*)alloc((size_t)n * 32 * 4);
  float*    B     = (float*)alloc((size_t)n * 32 * 4);
  float*    C     = (float*)alloc((size_t)n * 64 * 4);  // also staging (CSR build)
  uint32_t* cnt   = (uint32_t*)alloc((size_t)n * 4);
  float*    dinv  = (float*)alloc((size_t)n * 4);
  uint32_t* rowp  = (uint32_t*)alloc((size_t)(n + 1) * 4);
  uint32_t* esrc  = (uint32_t*)alloc((size_t)E * 4);
  uint32_t* gbcnt = (uint32_t*)alloc(512 * 4);
  uint32_t* bbase = (uint32_t*)alloc(512 * 4);
  uint32_t* gcur  = (uint32_t*)alloc(512 * 4);
  uint32_t* bsum  = (uint32_t*)alloc(512 * 4);
  uint32_t* staging = (uint32_t*)C;  // alias: C unused until layer 2
  (void)ws_size; (void)n_in; (void)out_size;

  uint32_t k1a, k1b, k2a, k2b;
  tf2x32(0u, 42u, 0u, 0u, k1a, k1b);
  tf2x32(0u, 42u, 0u, 1u, k2a, k2b);

  const int NB  = (n + 255) >> 8;           // buckets (391 for n=100k)
  const int nv  = n * 32;
  const int gN  = (n + 255) / 256;
  const int gN1 = (n + 1 + 255) / 256;
  const int gC  = (E + CHUNK - 1) / CHUNK;
  const int gV  = (nv + 255) / 256;
  const int gG1 = (n + 7) / 8;
  const int gG2 = (n + 3) / 4;
  dim3 blk(256);

  // ---- CSR build (bucketed; all scattered accesses in LDS) ----
  zero512<<<1, dim3(512), 0, stream>>>(gbcnt);
  kbhist<<<gC, blk, 0, stream>>>(dst, gbcnt, E, NB);
  kbscan<<<1, dim3(512), 0, stream>>>(gbcnt, bbase, gcur, NB);
  kbin<<<gC, blk, 0, stream>>>(src, dst, gcur, staging, E, NB);
  kcount<<<NB, blk, 0, stream>>>(staging, bbase, gbcnt, cnt, n);
  make_dinv<<<gN, blk, 0, stream>>>(cnt, dinv, n);
  scan1<<<gN, blk, 0, stream>>>(cnt, rowp, bsum, n);
  scan2<<<1, dim3(512), 0, stream>>>(bsum, gN);
  scan3<<<gN1, blk, 0, stream>>>(rowp, bsum, n, E);
  kplace<<<NB, blk, 0, stream>>>(staging, bbase, gbcnt, rowp, esrc, n);

  // ---- layer 1 ----
  gemm_n64_k32<<<gG1, blk, 0, stream>>>(x, W1, dinv, A, n);
  gather_fin<<<gV, blk, 0, stream>>>(A, rowp, esrc, dinv, b1, B, n, 3, k1a, k1b);

  // ---- layer 2 ----
  gather_fin<<<gV, blk, 0, stream>>>(B, rowp, esrc, dinv, nullptr, A, n, 0, 0u, 0u);
  gemm_k32_n64_act<<<gG2, blk, 0, stream>>>(A, W2, b2, C, k2a, k2b, n);

  // ---- layer 3 ----
  gemm_n64_k32<<<gG1, blk, 0, stream>>>(C, W3, dinv, A, n);
  gather_fin<<<gV, blk, 0, stream>>>(A, rowp, esrc, dinv, b3, out, n, 1, 0u, 0u);
}

// Round 4
// 400.487 us; speedup vs baseline: 10.5296x; 1.1735x over previous
//
#include <hip/hip_runtime.h>
#include <stdint.h>
#include <stddef.h>

// ---------------------------------------------------------------------------
// JAX threefry2x32 (partitionable mode — verified: absmax 2.4e-4).
// ---------------------------------------------------------------------------
__host__ __device__ __forceinline__ uint32_t rotl32(uint32_t v, uint32_t r) {
  return (v << r) | (v >> (32u - r));
}

__host__ __device__ __forceinline__ void tf2x32(uint32_t k0, uint32_t k1,
                                                uint32_t x0, uint32_t x1,
                                                uint32_t& o0, uint32_t& o1) {
  uint32_t ks2 = k0 ^ k1 ^ 0x1BD11BDAu;
  x0 += k0; x1 += k1;
  x0 += x1; x1 = rotl32(x1, 13); x1 ^= x0;
  x0 += x1; x1 = rotl32(x1, 15); x1 ^= x0;
  x0 += x1; x1 = rotl32(x1, 26); x1 ^= x0;
  x0 += x1; x1 = rotl32(x1, 6);  x1 ^= x0;
  x0 += k1; x1 += ks2 + 1u;
  x0 += x1; x1 = rotl32(x1, 17); x1 ^= x0;
  x0 += x1; x1 = rotl32(x1, 29); x1 ^= x0;
  x0 += x1; x1 = rotl32(x1, 16); x1 ^= x0;
  x0 += x1; x1 = rotl32(x1, 24); x1 ^= x0;
  x0 += ks2; x1 += k0 + 2u;
  x0 += x1; x1 = rotl32(x1, 13); x1 ^= x0;
  x0 += x1; x1 = rotl32(x1, 15); x1 ^= x0;
  x0 += x1; x1 = rotl32(x1, 26); x1 ^= x0;
  x0 += x1; x1 = rotl32(x1, 6);  x1 ^= x0;
  x0 += k0; x1 += k1 + 3u;
  x0 += x1; x1 = rotl32(x1, 17); x1 ^= x0;
  x0 += x1; x1 = rotl32(x1, 29); x1 ^= x0;
  x0 += x1; x1 = rotl32(x1, 16); x1 ^= x0;
  x0 += x1; x1 = rotl32(x1, 24); x1 ^= x0;
  x0 += k1; x1 += ks2 + 4u;
  x0 += x1; x1 = rotl32(x1, 13); x1 ^= x0;
  x0 += x1; x1 = rotl32(x1, 15); x1 ^= x0;
  x0 += x1; x1 = rotl32(x1, 26); x1 ^= x0;
  x0 += x1; x1 = rotl32(x1, 6);  x1 ^= x0;
  x0 += ks2; x1 += k0 + 5u;
  o0 = x0; o1 = x1;
}

__device__ __forceinline__ bool tf_keep(uint32_t k0, uint32_t k1, uint32_t idx) {
  uint32_t o0, o1;
  tf2x32(k0, k1, 0u, idx, o0, o1);
  return ((o0 ^ o1) >> 31) == 0u;
}

// ---------------------------------------------------------------------------
// Bucketed CSR build. Bucket b = dst>>8 (256 nodes/bucket).
// Staging entry: (dst&255)<<17 | src   (src < 2^17).
// ---------------------------------------------------------------------------
#define CHUNK 8192

__global__ __launch_bounds__(512) void zero512(uint32_t* __restrict__ p) {
  p[threadIdx.x] = 0u;
}

__global__ __launch_bounds__(256) void kbhist(const int* __restrict__ dst,
                                              uint32_t* __restrict__ gbcnt,
                                              int E, int NB) {
  __shared__ uint32_t lc[512];
  for (int i = threadIdx.x; i < NB; i += 256) lc[i] = 0u;
  __syncthreads();
  int base = blockIdx.x * CHUNK;
  int end = min(base + CHUNK, E);
  for (int i = base + threadIdx.x; i < end; i += 256)
    atomicAdd(&lc[((uint32_t)dst[i]) >> 8], 1u);
  __syncthreads();
  for (int i = threadIdx.x; i < NB; i += 256)
    if (lc[i]) atomicAdd(&gbcnt[i], lc[i]);
}

__global__ __launch_bounds__(512) void kbscan(const uint32_t* __restrict__ gbcnt,
                                              uint32_t* __restrict__ bbase,
                                              uint32_t* __restrict__ gcur, int NB) {
  __shared__ uint32_t s[512];
  int i = threadIdx.x;
  uint32_t v = (i < NB) ? gbcnt[i] : 0u;
  s[i] = v;
  __syncthreads();
  for (int off = 1; off < 512; off <<= 1) {
    uint32_t t = (i >= off) ? s[i - off] : 0u;
    __syncthreads();
    if (i >= off) s[i] += t;
    __syncthreads();
  }
  if (i < NB) {
    uint32_t e = s[i] - v;
    bbase[i] = e;
    gcur[i] = e;
  }
}

__global__ __launch_bounds__(256) void kbin(const int* __restrict__ src,
                                            const int* __restrict__ dst,
                                            uint32_t* __restrict__ gcur,
                                            uint32_t* __restrict__ staging,
                                            int E, int NB) {
  __shared__ uint32_t lcnt[512];
  __shared__ uint32_t lbase[512];
  for (int i = threadIdx.x; i < NB; i += 256) lcnt[i] = 0u;
  __syncthreads();
  int base = blockIdx.x * CHUNK;
  int end = min(base + CHUNK, E);
  for (int i = base + threadIdx.x; i < end; i += 256)
    atomicAdd(&lcnt[((uint32_t)dst[i]) >> 8], 1u);
  __syncthreads();
  for (int i = threadIdx.x; i < NB; i += 256) {
    uint32_t c = lcnt[i];
    lbase[i] = c ? atomicAdd(&gcur[i], c) : 0u;
    lcnt[i] = 0u;
  }
  __syncthreads();
  for (int i = base + threadIdx.x; i < end; i += 256) {
    uint32_t d = (uint32_t)dst[i];
    uint32_t b = d >> 8;
    uint32_t off = atomicAdd(&lcnt[b], 1u);
    staging[lbase[b] + off] = ((d & 255u) << 17) | (uint32_t)src[i];
  }
}

// Fused per-bucket: node counts -> LDS scan -> rowp/dinv -> placement.
// rowp[node] = bbase[b] + exclusive_scan_within_bucket(counts).
__global__ __launch_bounds__(256) void kfin(
    const uint32_t* __restrict__ staging, const uint32_t* __restrict__ bbase,
    const uint32_t* __restrict__ gbcnt, uint32_t* __restrict__ rowp,
    float* __restrict__ dinv, uint32_t* __restrict__ esrc, int n, int E) {
  __shared__ uint32_t lc[256];
  __shared__ uint32_t lofs[256];
  int tid = threadIdx.x;
  int b = blockIdx.x;
  lc[tid] = 0u;
  __syncthreads();
  uint32_t s = bbase[b], c = gbcnt[b];
  for (uint32_t i = tid; i < c; i += 256)
    atomicAdd(&lc[staging[s + i] >> 17], 1u);
  __syncthreads();
  uint32_t myc = lc[tid];
  lofs[tid] = myc;
  __syncthreads();
  for (int off = 1; off < 256; off <<= 1) {
    uint32_t t = (tid >= off) ? lofs[tid - off] : 0u;
    __syncthreads();
    if (tid >= off) lofs[tid] += t;
    __syncthreads();
  }
  uint32_t excl = s + lofs[tid] - myc;  // global CSR start for this node
  int node = (b << 8) + tid;
  if (node < n) {
    rowp[node] = excl;
    dinv[node] = 1.0f / sqrtf((float)(myc + 1u));
  }
  if (b == 0 && tid == 0) rowp[n] = (uint32_t)E;
  __syncthreads();
  lofs[tid] = excl;  // becomes cursor
  __syncthreads();
  for (uint32_t i = tid; i < c; i += 256) {
    uint32_t p = staging[s + i];
    uint32_t pos = atomicAdd(&lofs[p >> 17], 1u);
    esrc[pos] = p & 0x1FFFFu;
  }
}

// ---------------------------------------------------------------------------
// GEMM: out[n,32] = dinv[row] * (X[n,64] @ W[64,32]).
// 32 rows/block; thread: r = tid>>3, c4 = (tid&7)*4. Xs padded to stride 68.
// ---------------------------------------------------------------------------
__global__ __launch_bounds__(256) void gemm_n64_k32(
    const float* __restrict__ X, const float* __restrict__ W,
    const float* __restrict__ dinv, float* __restrict__ out, int n) {
  __shared__ float Ws[64 * 32];
  __shared__ float Xs[32 * 68];
  int tid = threadIdx.x;
  {
    const float4* Wv = (const float4*)W;
    float4* Wsv = (float4*)Ws;
    Wsv[tid] = Wv[tid];
    Wsv[tid + 256] = Wv[tid + 256];
  }
  int row0 = blockIdx.x * 32;
  {
    const float4* Xv = (const float4*)(X + (size_t)row0 * 64);
    int lim = (n - row0) * 16;  // valid float4 count
    float4 z = make_float4(0.f, 0.f, 0.f, 0.f);
    int i0 = tid, i1 = tid + 256;
    float4 v0 = (i0 < lim) ? Xv[i0] : z;
    float4 v1 = (i1 < lim) ? Xv[i1] : z;
    *(float4*)(Xs + (i0 >> 4) * 68 + ((i0 & 15) << 2)) = v0;
    *(float4*)(Xs + (i1 >> 4) * 68 + ((i1 & 15) << 2)) = v1;
  }
  __syncthreads();
  int r = tid >> 3;
  int c4 = (tid & 7) << 2;
  int row = row0 + r;
  if (row >= n) return;
  float4 acc = make_float4(0.f, 0.f, 0.f, 0.f);
#pragma unroll
  for (int k = 0; k < 64; k += 4) {
    float4 xv = *(const float4*)(Xs + r * 68 + k);
    float4 w0 = *(const float4*)(Ws + (k + 0) * 32 + c4);
    float4 w1 = *(const float4*)(Ws + (k + 1) * 32 + c4);
    float4 w2 = *(const float4*)(Ws + (k + 2) * 32 + c4);
    float4 w3 = *(const float4*)(Ws + (k + 3) * 32 + c4);
    acc.x = fmaf(xv.x, w0.x, acc.x); acc.y = fmaf(xv.x, w0.y, acc.y);
    acc.z = fmaf(xv.x, w0.z, acc.z); acc.w = fmaf(xv.x, w0.w, acc.w);
    acc.x = fmaf(xv.y, w1.x, acc.x); acc.y = fmaf(xv.y, w1.y, acc.y);
    acc.z = fmaf(xv.y, w1.z, acc.z); acc.w = fmaf(xv.y, w1.w, acc.w);
    acc.x = fmaf(xv.z, w2.x, acc.x); acc.y = fmaf(xv.z, w2.y, acc.y);
    acc.z = fmaf(xv.z, w2.z, acc.z); acc.w = fmaf(xv.z, w2.w, acc.w);
    acc.x = fmaf(xv.w, w3.x, acc.x); acc.y = fmaf(xv.w, w3.y, acc.y);
    acc.z = fmaf(xv.w, w3.z, acc.z); acc.w = fmaf(xv.w, w3.w, acc.w);
  }
  float dj = dinv[row];
  acc.x *= dj; acc.y *= dj; acc.z *= dj; acc.w *= dj;
  *(float4*)(out + (size_t)row * 32 + c4) = acc;
}

// ---------------------------------------------------------------------------
// GEMM: out[n,64] = dropout(celu(X[n,32] @ W[32,64] + b)).
// 16 rows/block; thread: r = tid>>4, c4 = (tid&15)*4. Xs padded to stride 36.
// ---------------------------------------------------------------------------
__global__ __launch_bounds__(256) void gemm_k32_n64_act(
    const float* __restrict__ X, const float* __restrict__ W,
    const float* __restrict__ bias, float* __restrict__ out,
    uint32_t k0, uint32_t k1, int n) {
  __shared__ float Ws[32 * 64];
  __shared__ float Xs[16 * 36];
  int tid = threadIdx.x;
  {
    const float4* Wv = (const float4*)W;
    float4* Wsv = (float4*)Ws;
    Wsv[tid] = Wv[tid];
    Wsv[tid + 256] = Wv[tid + 256];
  }
  int row0 = blockIdx.x * 16;
  if (tid < 128) {
    const float4* Xv = (const float4*)(X + (size_t)row0 * 32);
    int lim = (n - row0) * 8;
    float4 z = make_float4(0.f, 0.f, 0.f, 0.f);
    float4 v = (tid < lim) ? Xv[tid] : z;
    *(float4*)(Xs + (tid >> 3) * 36 + ((tid & 7) << 2)) = v;
  }
  __syncthreads();
  int r = tid >> 4;
  int c4 = (tid & 15) << 2;
  int row = row0 + r;
  if (row >= n) return;
  float4 acc = make_float4(0.f, 0.f, 0.f, 0.f);
#pragma unroll
  for (int k = 0; k < 32; k += 4) {
    float4 xv = *(const float4*)(Xs + r * 36 + k);
    float4 w0 = *(const float4*)(Ws + (k + 0) * 64 + c4);
    float4 w1 = *(const float4*)(Ws + (k + 1) * 64 + c4);
    float4 w2 = *(const float4*)(Ws + (k + 2) * 64 + c4);
    float4 w3 = *(const float4*)(Ws + (k + 3) * 64 + c4);
    acc.x = fmaf(xv.x, w0.x, acc.x); acc.y = fmaf(xv.x, w0.y, acc.y);
    acc.z = fmaf(xv.x, w0.z, acc.z); acc.w = fmaf(xv.x, w0.w, acc.w);
    acc.x = fmaf(xv.y, w1.x, acc.x); acc.y = fmaf(xv.y, w1.y, acc.y);
    acc.z = fmaf(xv.y, w1.z, acc.z); acc.w = fmaf(xv.y, w1.w, acc.w);
    acc.x = fmaf(xv.z, w2.x, acc.x); acc.y = fmaf(xv.z, w2.y, acc.y);
    acc.z = fmaf(xv.z, w2.z, acc.z); acc.w = fmaf(xv.z, w2.w, acc.w);
    acc.x = fmaf(xv.w, w3.x, acc.x); acc.y = fmaf(xv.w, w3.y, acc.y);
    acc.z = fmaf(xv.w, w3.z, acc.z); acc.w = fmaf(xv.w, w3.w, acc.w);
  }
  float4 bv = *(const float4*)(bias + c4);
  float vv[4] = {acc.x + bv.x, acc.y + bv.y, acc.z + bv.z, acc.w + bv.w};
  uint32_t base = (uint32_t)row * 64u + (uint32_t)c4;
#pragma unroll
  for (int q = 0; q < 4; ++q) {
    float v = vv[q];
    v = v > 0.f ? v : expm1f(v);
    vv[q] = tf_keep(k0, k1, base + q) ? v * 2.f : 0.f;
  }
  *(float4*)(out + (size_t)row * 64 + c4) = make_float4(vv[0], vv[1], vv[2], vv[3]);
}

// ---------------------------------------------------------------------------
// Gather-reduce: 32 lanes per dst j. lane l: eslot = l>>3 (edge slot),
// c4 = (l&7)*4 (dim chunk). float4 row loads; shuffle reduce; scalar epilogue
// redistributed so all lanes are active for threefry.
// ---------------------------------------------------------------------------
__global__ __launch_bounds__(256) void gather_fin(
    const float* __restrict__ hs, const uint32_t* __restrict__ rowp,
    const uint32_t* __restrict__ esrc, const float* __restrict__ dinv,
    const float* __restrict__ bias, float* __restrict__ out,
    int n, int mode, uint32_t k0, uint32_t k1) {
  int gt = blockIdx.x * 256 + threadIdx.x;
  int j = gt >> 5;
  if (j >= n) return;
  int l = threadIdx.x & 31;
  int eslot = l >> 3;
  int c4 = (l & 7) << 2;
  float4 acc = make_float4(0.f, 0.f, 0.f, 0.f);
  uint32_t e1 = rowp[j + 1];
  uint32_t e = rowp[j] + (uint32_t)eslot;
  for (; e + 4 < e1; e += 8) {
    uint32_t s0 = esrc[e];
    uint32_t s1 = esrc[e + 4];
    float4 v0 = *(const float4*)(hs + ((size_t)s0 << 5) + c4);
    float4 v1 = *(const float4*)(hs + ((size_t)s1 << 5) + c4);
    acc.x += v0.x + v1.x;
    acc.y += v0.y + v1.y;
    acc.z += v0.z + v1.z;
    acc.w += v0.w + v1.w;
  }
  if (e < e1) {
    uint32_t s0 = esrc[e];
    float4 v0 = *(const float4*)(hs + ((size_t)s0 << 5) + c4);
    acc.x += v0.x; acc.y += v0.y; acc.z += v0.z; acc.w += v0.w;
  }
  // reduce across the 4 eslot groups (lane^8, lane^16 stay within each 32-half)
  acc.x += __shfl_xor(acc.x, 8);  acc.y += __shfl_xor(acc.y, 8);
  acc.z += __shfl_xor(acc.z, 8);  acc.w += __shfl_xor(acc.w, 8);
  acc.x += __shfl_xor(acc.x, 16); acc.y += __shfl_xor(acc.y, 16);
  acc.z += __shfl_xor(acc.z, 16); acc.w += __shfl_xor(acc.w, 16);
  // redistribute: lane l takes dim d=l from chunk d>>2 (held by lane (tid&32)|(d>>2))
  int srcLane = (threadIdx.x & 32) | (l >> 2);
  float va = __shfl(acc.x, srcLane);
  float vb = __shfl(acc.y, srcLane);
  float vc = __shfl(acc.z, srcLane);
  float vd = __shfl(acc.w, srcLane);
  float lo = (l & 1) ? vb : va;
  float hi = (l & 1) ? vd : vc;
  float sum = (l & 2) ? hi : lo;
  sum += hs[gt];  // self-loop term (already dinv[src]-scaled)
  float dj = dinv[j];
  float v = dj * sum;
  if (mode == 1) {
    v += bias[l];
    v = v > 0.f ? v : expm1f(v);
  } else if (mode == 3) {
    v += bias[l];
    v = v > 0.f ? v : expm1f(v);
    v = tf_keep(k0, k1, (uint32_t)gt) ? v * 2.f : 0.f;
    v *= dj;
  }
  out[gt] = v;
}

// ---------------------------------------------------------------------------
extern "C" void kernel_launch(void* const* d_in, const int* in_sizes, int n_in,
                              void* d_out, int out_size, void* d_ws, size_t ws_size,
                              hipStream_t stream) {
  const float* x  = (const float*)d_in[0];
  const int*   ei = (const int*)d_in[1];
  const float* W1 = (const float*)d_in[2];
  const float* b1 = (const float*)d_in[3];
  const float* W2 = (const float*)d_in[4];
  const float* b2 = (const float*)d_in[5];
  const float* W3 = (const float*)d_in[6];
  const float* b3 = (const float*)d_in[7];
  float* out = (float*)d_out;

  const int n = in_sizes[0] / 64;
  const int E = in_sizes[1] / 2;
  const int* src = ei;
  const int* dst = ei + E;

  char* ws = (char*)d_ws;
  size_t off = 0;
  auto alloc = [&](size_t bytes) {
    void* p = ws + off;
    off = (off + bytes + 255) & ~(size_t)255;
    return p;
  };
  float*    A     = (float*)alloc((size_t)n * 32 * 4);
  float*    B     = (float*)alloc((size_t)n * 32 * 4);
  float*    C     = (float*)alloc((size_t)n * 64 * 4);  // aliased as staging
  float*    dinv  = (float*)alloc((size_t)n * 4);
  uint32_t* rowp  = (uint32_t*)alloc((size_t)(n + 1) * 4);
  uint32_t* esrc  = (uint32_t*)alloc((size_t)E * 4);
  uint32_t* gbcnt = (uint32_t*)alloc(512 * 4);
  uint32_t* bbase = (uint32_t*)alloc(512 * 4);
  uint32_t* gcur  = (uint32_t*)alloc(512 * 4);
  uint32_t* staging = (uint32_t*)C;  // C unused until layer 2
  (void)ws_size; (void)n_in; (void)out_size;

  uint32_t k1a, k1b, k2a, k2b;
  tf2x32(0u, 42u, 0u, 0u, k1a, k1b);
  tf2x32(0u, 42u, 0u, 1u, k2a, k2b);

  const int NB  = (n + 255) >> 8;
  const int nv  = n * 32;
  const int gC  = (E + CHUNK - 1) / CHUNK;
  const int gV  = (nv + 255) / 256;
  const int gG1 = (n + 31) / 32;
  const int gG2 = (n + 15) / 16;
  dim3 blk(256);

  // ---- CSR build ----
  zero512<<<1, dim3(512), 0, stream>>>(gbcnt);
  kbhist<<<gC, blk, 0, stream>>>(dst, gbcnt, E, NB);
  kbscan<<<1, dim3(512), 0, stream>>>(gbcnt, bbase, gcur, NB);
  kbin<<<gC, blk, 0, stream>>>(src, dst, gcur, staging, E, NB);
  kfin<<<NB, blk, 0, stream>>>(staging, bbase, gbcnt, rowp, dinv, esrc, n, E);

  // ---- layer 1 ----
  gemm_n64_k32<<<gG1, blk, 0, stream>>>(x, W1, dinv, A, n);
  gather_fin<<<gV, blk, 0, stream>>>(A, rowp, esrc, dinv, b1, B, n, 3, k1a, k1b);

  // ---- layer 2 ----
  gather_fin<<<gV, blk, 0, stream>>>(B, rowp, esrc, dinv, nullptr, A, n, 0, 0u, 0u);
  gemm_k32_n64_act<<<gG2, blk, 0, stream>>>(A, W2, b2, C, k2a, k2b, n);

  // ---- layer 3 ----
  gemm_n64_k32<<<gG1, blk, 0, stream>>>(C, W3, dinv, A, n);
  gather_fin<<<gV, blk, 0, stream>>>(A, rowp, esrc, dinv, b3, out, n, 1, 0u, 0u);
}

// Round 5
// 395.340 us; speedup vs baseline: 10.6667x; 1.0130x over previous
//
#include <hip/hip_runtime.h>
#include <stdint.h>
#include <stddef.h>

// ---------------------------------------------------------------------------
// JAX threefry2x32 (partitionable mode — verified: absmax 2.4e-4).
// ---------------------------------------------------------------------------
__host__ __device__ __forceinline__ uint32_t rotl32(uint32_t v, uint32_t r) {
  return (v << r) | (v >> (32u - r));
}

__host__ __device__ __forceinline__ void tf2x32(uint32_t k0, uint32_t k1,
                                                uint32_t x0, uint32_t x1,
                                                uint32_t& o0, uint32_t& o1) {
  uint32_t ks2 = k0 ^ k1 ^ 0x1BD11BDAu;
  x0 += k0; x1 += k1;
  x0 += x1; x1 = rotl32(x1, 13); x1 ^= x0;
  x0 += x1; x1 = rotl32(x1, 15); x1 ^= x0;
  x0 += x1; x1 = rotl32(x1, 26); x1 ^= x0;
  x0 += x1; x1 = rotl32(x1, 6);  x1 ^= x0;
  x0 += k1; x1 += ks2 + 1u;
  x0 += x1; x1 = rotl32(x1, 17); x1 ^= x0;
  x0 += x1; x1 = rotl32(x1, 29); x1 ^= x0;
  x0 += x1; x1 = rotl32(x1, 16); x1 ^= x0;
  x0 += x1; x1 = rotl32(x1, 24); x1 ^= x0;
  x0 += ks2; x1 += k0 + 2u;
  x0 += x1; x1 = rotl32(x1, 13); x1 ^= x0;
  x0 += x1; x1 = rotl32(x1, 15); x1 ^= x0;
  x0 += x1; x1 = rotl32(x1, 26); x1 ^= x0;
  x0 += x1; x1 = rotl32(x1, 6);  x1 ^= x0;
  x0 += k0; x1 += k1 + 3u;
  x0 += x1; x1 = rotl32(x1, 17); x1 ^= x0;
  x0 += x1; x1 = rotl32(x1, 29); x1 ^= x0;
  x0 += x1; x1 = rotl32(x1, 16); x1 ^= x0;
  x0 += x1; x1 = rotl32(x1, 24); x1 ^= x0;
  x0 += k1; x1 += ks2 + 4u;
  x0 += x1; x1 = rotl32(x1, 13); x1 ^= x0;
  x0 += x1; x1 = rotl32(x1, 15); x1 ^= x0;
  x0 += x1; x1 = rotl32(x1, 26); x1 ^= x0;
  x0 += x1; x1 = rotl32(x1, 6);  x1 ^= x0;
  x0 += ks2; x1 += k0 + 5u;
  o0 = x0; o1 = x1;
}

__device__ __forceinline__ bool tf_keep(uint32_t k0, uint32_t k1, uint32_t idx) {
  uint32_t o0, o1;
  tf2x32(k0, k1, 0u, idx, o0, o1);
  return ((o0 ^ o1) >> 31) == 0u;
}

// ---------------------------------------------------------------------------
// Bucketed CSR build. Bucket b = dst>>7 (128 nodes/bucket, NB<=1024).
// Staging entry: (dst&127)<<17 | src   (src < 2^17).
// CHUNK=2048 -> NBLK chunk-blocks; tbl[blk*NB + b] = per-(chunk,bucket) count,
// then exclusive prefix within each bucket column.
// ---------------------------------------------------------------------------
#define CHUNK 2048

__global__ __launch_bounds__(256) void k1_hist(const int* __restrict__ dst,
                                               uint32_t* __restrict__ tbl,
                                               int E, int NB) {
  __shared__ uint32_t lc[1024];
  int tid = threadIdx.x;
  for (int i = tid; i < NB; i += 256) lc[i] = 0u;
  __syncthreads();
  int base = blockIdx.x * CHUNK;
  int end = min(base + CHUNK, E);
  for (int i = base + tid; i < end; i += 256)
    atomicAdd(&lc[((uint32_t)dst[i]) >> 7], 1u);
  __syncthreads();
  uint32_t* row = tbl + (size_t)blockIdx.x * NB;
  for (int i = tid; i < NB; i += 256) row[i] = lc[i];
}

// One block per bucket: exclusive scan down the column; gbcnt[b] = total.
__global__ __launch_bounds__(256) void k2_scan(uint32_t* __restrict__ tbl,
                                               uint32_t* __restrict__ gbcnt,
                                               int NBLK, int NB) {
  __shared__ uint32_t s[256];
  int tid = threadIdx.x;
  int b = blockIdx.x;
  uint32_t carry = 0u;
  for (int t = 0; t < NBLK; t += 256) {
    int blk = t + tid;
    uint32_t v = (blk < NBLK) ? tbl[(size_t)blk * NB + b] : 0u;
    s[tid] = v;
    __syncthreads();
    for (int off = 1; off < 256; off <<= 1) {
      uint32_t u = (tid >= off) ? s[tid - off] : 0u;
      __syncthreads();
      if (tid >= off) s[tid] += u;
      __syncthreads();
    }
    uint32_t excl = s[tid] - v;
    if (blk < NBLK) tbl[(size_t)blk * NB + b] = carry + excl;
    uint32_t tot = s[255];
    __syncthreads();
    carry += tot;
  }
  if (tid == 0) gbcnt[b] = carry;
}

// Exclusive scan of gbcnt -> bbase (NB <= 1024, one block).
__global__ __launch_bounds__(1024) void k3_bscan(const uint32_t* __restrict__ gbcnt,
                                                 uint32_t* __restrict__ bbase, int NB) {
  __shared__ uint32_t s[1024];
  int i = threadIdx.x;
  uint32_t v = (i < NB) ? gbcnt[i] : 0u;
  s[i] = v;
  __syncthreads();
  for (int off = 1; off < 1024; off <<= 1) {
    uint32_t t = (i >= off) ? s[i - off] : 0u;
    __syncthreads();
    if (i >= off) s[i] += t;
    __syncthreads();
  }
  if (i < NB) bbase[i] = s[i] - v;
}

// Bin edges into bucket-contiguous staging; bases precomputed (no count pass).
__global__ __launch_bounds__(256) void k4_bin(const int* __restrict__ src,
                                              const int* __restrict__ dst,
                                              const uint32_t* __restrict__ tbl,
                                              const uint32_t* __restrict__ bbase,
                                              uint32_t* __restrict__ staging,
                                              int E, int NB) {
  __shared__ uint32_t lbase[1024];
  __shared__ uint32_t lcnt[1024];
  int tid = threadIdx.x;
  const uint32_t* row = tbl + (size_t)blockIdx.x * NB;
  for (int i = tid; i < NB; i += 256) {
    lbase[i] = row[i] + bbase[i];
    lcnt[i] = 0u;
  }
  __syncthreads();
  int base = blockIdx.x * CHUNK;
  int end = min(base + CHUNK, E);
  for (int i = base + tid; i < end; i += 256) {
    uint32_t d = (uint32_t)dst[i];
    uint32_t b = d >> 7;
    uint32_t off = atomicAdd(&lcnt[b], 1u);
    staging[lbase[b] + off] = ((d & 127u) << 17) | (uint32_t)src[i];
  }
}

// Fused per-bucket: node counts -> LDS scan -> rowp/dinv -> placement.
__global__ __launch_bounds__(256) void k5_fin(
    const uint32_t* __restrict__ staging, const uint32_t* __restrict__ bbase,
    const uint32_t* __restrict__ gbcnt, uint32_t* __restrict__ rowp,
    float* __restrict__ dinv, uint32_t* __restrict__ esrc, int n, int E) {
  __shared__ uint32_t lc[128];
  __shared__ uint32_t sc[128];
  __shared__ uint32_t lcur[128];
  int tid = threadIdx.x;
  int b = blockIdx.x;
  if (tid < 128) lc[tid] = 0u;
  __syncthreads();
  uint32_t s = bbase[b], c = gbcnt[b];
  for (uint32_t i = tid; i < c; i += 256)
    atomicAdd(&lc[staging[s + i] >> 17], 1u);
  __syncthreads();
  uint32_t myc = (tid < 128) ? lc[tid] : 0u;
  if (tid < 128) sc[tid] = myc;
  __syncthreads();
  for (int off = 1; off < 128; off <<= 1) {
    uint32_t t = (tid < 128 && tid >= off) ? sc[tid - off] : 0u;
    __syncthreads();
    if (tid < 128 && tid >= off) sc[tid] += t;
    __syncthreads();
  }
  if (tid < 128) {
    uint32_t gstart = s + sc[tid] - myc;
    int node = (b << 7) + tid;
    if (node < n) {
      rowp[node] = gstart;
      dinv[node] = 1.0f / sqrtf((float)(myc + 1u));
    }
    lcur[tid] = gstart;
  }
  if (b == 0 && tid == 0) rowp[n] = (uint32_t)E;
  __syncthreads();
  for (uint32_t i = tid; i < c; i += 256) {
    uint32_t p = staging[s + i];
    uint32_t pos = atomicAdd(&lcur[p >> 17], 1u);
    esrc[pos] = p & 0x1FFFFu;
  }
}

// ---------------------------------------------------------------------------
// GEMM: out[n,32] = dinv[row] * (X[n,64] @ W[64,32]).
// ---------------------------------------------------------------------------
__global__ __launch_bounds__(256) void gemm_n64_k32(
    const float* __restrict__ X, const float* __restrict__ W,
    const float* __restrict__ dinv, float* __restrict__ out, int n) {
  __shared__ float Ws[64 * 32];
  __shared__ float Xs[32 * 68];
  int tid = threadIdx.x;
  {
    const float4* Wv = (const float4*)W;
    float4* Wsv = (float4*)Ws;
    Wsv[tid] = Wv[tid];
    Wsv[tid + 256] = Wv[tid + 256];
  }
  int row0 = blockIdx.x * 32;
  {
    const float4* Xv = (const float4*)(X + (size_t)row0 * 64);
    int lim = (n - row0) * 16;
    float4 z = make_float4(0.f, 0.f, 0.f, 0.f);
    int i0 = tid, i1 = tid + 256;
    float4 v0 = (i0 < lim) ? Xv[i0] : z;
    float4 v1 = (i1 < lim) ? Xv[i1] : z;
    *(float4*)(Xs + (i0 >> 4) * 68 + ((i0 & 15) << 2)) = v0;
    *(float4*)(Xs + (i1 >> 4) * 68 + ((i1 & 15) << 2)) = v1;
  }
  __syncthreads();
  int r = tid >> 3;
  int c4 = (tid & 7) << 2;
  int row = row0 + r;
  if (row >= n) return;
  float4 acc = make_float4(0.f, 0.f, 0.f, 0.f);
#pragma unroll
  for (int k = 0; k < 64; k += 4) {
    float4 xv = *(const float4*)(Xs + r * 68 + k);
    float4 w0 = *(const float4*)(Ws + (k + 0) * 32 + c4);
    float4 w1 = *(const float4*)(Ws + (k + 1) * 32 + c4);
    float4 w2 = *(const float4*)(Ws + (k + 2) * 32 + c4);
    float4 w3 = *(const float4*)(Ws + (k + 3) * 32 + c4);
    acc.x = fmaf(xv.x, w0.x, acc.x); acc.y = fmaf(xv.x, w0.y, acc.y);
    acc.z = fmaf(xv.x, w0.z, acc.z); acc.w = fmaf(xv.x, w0.w, acc.w);
    acc.x = fmaf(xv.y, w1.x, acc.x); acc.y = fmaf(xv.y, w1.y, acc.y);
    acc.z = fmaf(xv.y, w1.z, acc.z); acc.w = fmaf(xv.y, w1.w, acc.w);
    acc.x = fmaf(xv.z, w2.x, acc.x); acc.y = fmaf(xv.z, w2.y, acc.y);
    acc.z = fmaf(xv.z, w2.z, acc.z); acc.w = fmaf(xv.z, w2.w, acc.w);
    acc.x = fmaf(xv.w, w3.x, acc.x); acc.y = fmaf(xv.w, w3.y, acc.y);
    acc.z = fmaf(xv.w, w3.z, acc.z); acc.w = fmaf(xv.w, w3.w, acc.w);
  }
  float dj = dinv[row];
  acc.x *= dj; acc.y *= dj; acc.z *= dj; acc.w *= dj;
  *(float4*)(out + (size_t)row * 32 + c4) = acc;
}

// ---------------------------------------------------------------------------
// GEMM: out[n,64] = dropout(celu(X[n,32] @ W[32,64] + b)).
// ---------------------------------------------------------------------------
__global__ __launch_bounds__(256) void gemm_k32_n64_act(
    const float* __restrict__ X, const float* __restrict__ W,
    const float* __restrict__ bias, float* __restrict__ out,
    uint32_t k0, uint32_t k1, int n) {
  __shared__ float Ws[32 * 64];
  __shared__ float Xs[16 * 36];
  int tid = threadIdx.x;
  {
    const float4* Wv = (const float4*)W;
    float4* Wsv = (float4*)Ws;
    Wsv[tid] = Wv[tid];
    Wsv[tid + 256] = Wv[tid + 256];
  }
  int row0 = blockIdx.x * 16;
  if (tid < 128) {
    const float4* Xv = (const float4*)(X + (size_t)row0 * 32);
    int lim = (n - row0) * 8;
    float4 z = make_float4(0.f, 0.f, 0.f, 0.f);
    float4 v = (tid < lim) ? Xv[tid] : z;
    *(float4*)(Xs + (tid >> 3) * 36 + ((tid & 7) << 2)) = v;
  }
  __syncthreads();
  int r = tid >> 4;
  int c4 = (tid & 15) << 2;
  int row = row0 + r;
  if (row >= n) return;
  float4 acc = make_float4(0.f, 0.f, 0.f, 0.f);
#pragma unroll
  for (int k = 0; k < 32; k += 4) {
    float4 xv = *(const float4*)(Xs + r * 36 + k);
    float4 w0 = *(const float4*)(Ws + (k + 0) * 64 + c4);
    float4 w1 = *(const float4*)(Ws + (k + 1) * 64 + c4);
    float4 w2 = *(const float4*)(Ws + (k + 2) * 64 + c4);
    float4 w3 = *(const float4*)(Ws + (k + 3) * 64 + c4);
    acc.x = fmaf(xv.x, w0.x, acc.x); acc.y = fmaf(xv.x, w0.y, acc.y);
    acc.z = fmaf(xv.x, w0.z, acc.z); acc.w = fmaf(xv.x, w0.w, acc.w);
    acc.x = fmaf(xv.y, w1.x, acc.x); acc.y = fmaf(xv.y, w1.y, acc.y);
    acc.z = fmaf(xv.y, w1.z, acc.z); acc.w = fmaf(xv.y, w1.w, acc.w);
    acc.x = fmaf(xv.z, w2.x, acc.x); acc.y = fmaf(xv.z, w2.y, acc.y);
    acc.z = fmaf(xv.z, w2.z, acc.z); acc.w = fmaf(xv.z, w2.w, acc.w);
    acc.x = fmaf(xv.w, w3.x, acc.x); acc.y = fmaf(xv.w, w3.y, acc.y);
    acc.z = fmaf(xv.w, w3.z, acc.z); acc.w = fmaf(xv.w, w3.w, acc.w);
  }
  float4 bv = *(const float4*)(bias + c4);
  float vv[4] = {acc.x + bv.x, acc.y + bv.y, acc.z + bv.z, acc.w + bv.w};
  uint32_t base = (uint32_t)row * 64u + (uint32_t)c4;
#pragma unroll
  for (int q = 0; q < 4; ++q) {
    float v = vv[q];
    v = v > 0.f ? v : expm1f(v);
    vv[q] = tf_keep(k0, k1, base + q) ? v * 2.f : 0.f;
  }
  *(float4*)(out + (size_t)row * 64 + c4) = make_float4(vv[0], vv[1], vv[2], vv[3]);
}

// ---------------------------------------------------------------------------
// Gather-reduce: 32 lanes per dst j (4 edge slots x 8 dim-chunks), float4 rows,
// shuffle reduce, lane-permute redistribution, fused epilogue.
// ---------------------------------------------------------------------------
__global__ __launch_bounds__(256) void gather_fin(
    const float* __restrict__ hs, const uint32_t* __restrict__ rowp,
    const uint32_t* __restrict__ esrc, const float* __restrict__ dinv,
    const float* __restrict__ bias, float* __restrict__ out,
    int n, int mode, uint32_t k0, uint32_t k1) {
  int gt = blockIdx.x * 256 + threadIdx.x;
  int j = gt >> 5;
  if (j >= n) return;
  int l = threadIdx.x & 31;
  int eslot = l >> 3;
  int c4 = (l & 7) << 2;
  float4 acc = make_float4(0.f, 0.f, 0.f, 0.f);
  uint32_t e1 = rowp[j + 1];
  uint32_t e = rowp[j] + (uint32_t)eslot;
  for (; e + 4 < e1; e += 8) {
    uint32_t s0 = esrc[e];
    uint32_t s1 = esrc[e + 4];
    float4 v0 = *(const float4*)(hs + ((size_t)s0 << 5) + c4);
    float4 v1 = *(const float4*)(hs + ((size_t)s1 << 5) + c4);
    acc.x += v0.x + v1.x;
    acc.y += v0.y + v1.y;
    acc.z += v0.z + v1.z;
    acc.w += v0.w + v1.w;
  }
  if (e < e1) {
    uint32_t s0 = esrc[e];
    float4 v0 = *(const float4*)(hs + ((size_t)s0 << 5) + c4);
    acc.x += v0.x; acc.y += v0.y; acc.z += v0.z; acc.w += v0.w;
  }
  acc.x += __shfl_xor(acc.x, 8);  acc.y += __shfl_xor(acc.y, 8);
  acc.z += __shfl_xor(acc.z, 8);  acc.w += __shfl_xor(acc.w, 8);
  acc.x += __shfl_xor(acc.x, 16); acc.y += __shfl_xor(acc.y, 16);
  acc.z += __shfl_xor(acc.z, 16); acc.w += __shfl_xor(acc.w, 16);
  int srcLane = (threadIdx.x & 32) | (l >> 2);
  float va = __shfl(acc.x, srcLane);
  float vb = __shfl(acc.y, srcLane);
  float vc = __shfl(acc.z, srcLane);
  float vd = __shfl(acc.w, srcLane);
  float lo = (l & 1) ? vb : va;
  float hi = (l & 1) ? vd : vc;
  float sum = (l & 2) ? hi : lo;
  sum += hs[gt];
  float dj = dinv[j];
  float v = dj * sum;
  if (mode == 1) {
    v += bias[l];
    v = v > 0.f ? v : expm1f(v);
  } else if (mode == 3) {
    v += bias[l];
    v = v > 0.f ? v : expm1f(v);
    v = tf_keep(k0, k1, (uint32_t)gt) ? v * 2.f : 0.f;
    v *= dj;
  }
  out[gt] = v;
}

// ---------------------------------------------------------------------------
extern "C" void kernel_launch(void* const* d_in, const int* in_sizes, int n_in,
                              void* d_out, int out_size, void* d_ws, size_t ws_size,
                              hipStream_t stream) {
  const float* x  = (const float*)d_in[0];
  const int*   ei = (const int*)d_in[1];
  const float* W1 = (const float*)d_in[2];
  const float* b1 = (const float*)d_in[3];
  const float* W2 = (const float*)d_in[4];
  const float* b2 = (const float*)d_in[5];
  const float* W3 = (const float*)d_in[6];
  const float* b3 = (const float*)d_in[7];
  float* out = (float*)d_out;

  const int n = in_sizes[0] / 64;
  const int E = in_sizes[1] / 2;
  const int* src = ei;
  const int* dst = ei + E;

  char* ws = (char*)d_ws;
  size_t off = 0;
  auto alloc = [&](size_t bytes) {
    void* p = ws + off;
    off = (off + bytes + 255) & ~(size_t)255;
    return p;
  };
  float*    A     = (float*)alloc((size_t)n * 32 * 4);
  float*    B     = (float*)alloc((size_t)n * 32 * 4);
  float*    C     = (float*)alloc((size_t)n * 64 * 4);  // aliased as staging
  float*    dinv  = (float*)alloc((size_t)n * 4);
  uint32_t* rowp  = (uint32_t*)alloc((size_t)(n + 1) * 4);
  uint32_t* esrc  = (uint32_t*)alloc((size_t)E * 4);    // aliased as tbl
  uint32_t* gbcnt = (uint32_t*)alloc(1024 * 4);
  uint32_t* bbase = (uint32_t*)alloc(1024 * 4);
  uint32_t* staging = (uint32_t*)C;   // C unused until layer 2
  uint32_t* tbl     = esrc;           // tbl dead before esrc is written (k5)
  (void)ws_size; (void)n_in; (void)out_size;

  uint32_t k1a, k1b, k2a, k2b;
  tf2x32(0u, 42u, 0u, 0u, k1a, k1b);
  tf2x32(0u, 42u, 0u, 1u, k2a, k2b);

  const int NB   = (n + 127) >> 7;              // 782 buckets
  const int NBLK = (E + CHUNK - 1) / CHUNK;     // 1563 chunk-blocks
  const int nv   = n * 32;
  const int gV   = (nv + 255) / 256;
  const int gG1  = (n + 31) / 32;
  const int gG2  = (n + 15) / 16;
  dim3 blk(256);

  // tbl must fit in esrc: NBLK*NB*4 = 4.9 MB <= E*4 = 12.8 MB (holds for this problem)

  // ---- CSR build ----
  k1_hist<<<NBLK, blk, 0, stream>>>(dst, tbl, E, NB);
  k2_scan<<<NB, blk, 0, stream>>>(tbl, gbcnt, NBLK, NB);
  k3_bscan<<<1, dim3(1024), 0, stream>>>(gbcnt, bbase, NB);
  k4_bin<<<NBLK, blk, 0, stream>>>(src, dst, tbl, bbase, staging, E, NB);
  k5_fin<<<NB, blk, 0, stream>>>(staging, bbase, gbcnt, rowp, dinv, esrc, n, E);

  // ---- layer 1 ----
  gemm_n64_k32<<<gG1, blk, 0, stream>>>(x, W1, dinv, A, n);
  gather_fin<<<gV, blk, 0, stream>>>(A, rowp, esrc, dinv, b1, B, n, 3, k1a, k1b);

  // ---- layer 2 ----
  gather_fin<<<gV, blk, 0, stream>>>(B, rowp, esrc, dinv, nullptr, A, n, 0, 0u, 0u);
  gemm_k32_n64_act<<<gG2, blk, 0, stream>>>(A, W2, b2, C, k2a, k2b, n);

  // ---- layer 3 ----
  gemm_n64_k32<<<gG1, blk, 0, stream>>>(C, W3, dinv, A, n);
  gather_fin<<<gV, blk, 0, stream>>>(A, rowp, esrc, dinv, b3, out, n, 1, 0u, 0u);
}

// Round 6
// 381.304 us; speedup vs baseline: 11.0594x; 1.0368x over previous
//
#include <hip/hip_runtime.h>
#include <stdint.h>
#include <stddef.h>

// ---------------------------------------------------------------------------
// JAX threefry2x32 (partitionable mode — verified: absmax 2.4e-4).
// ---------------------------------------------------------------------------
__host__ __device__ __forceinline__ uint32_t rotl32(uint32_t v, uint32_t r) {
  return (v << r) | (v >> (32u - r));
}

__host__ __device__ __forceinline__ void tf2x32(uint32_t k0, uint32_t k1,
                                                uint32_t x0, uint32_t x1,
                                                uint32_t& o0, uint32_t& o1) {
  uint32_t ks2 = k0 ^ k1 ^ 0x1BD11BDAu;
  x0 += k0; x1 += k1;
  x0 += x1; x1 = rotl32(x1, 13); x1 ^= x0;
  x0 += x1; x1 = rotl32(x1, 15); x1 ^= x0;
  x0 += x1; x1 = rotl32(x1, 26); x1 ^= x0;
  x0 += x1; x1 = rotl32(x1, 6);  x1 ^= x0;
  x0 += k1; x1 += ks2 + 1u;
  x0 += x1; x1 = rotl32(x1, 17); x1 ^= x0;
  x0 += x1; x1 = rotl32(x1, 29); x1 ^= x0;
  x0 += x1; x1 = rotl32(x1, 16); x1 ^= x0;
  x0 += x1; x1 = rotl32(x1, 24); x1 ^= x0;
  x0 += ks2; x1 += k0 + 2u;
  x0 += x1; x1 = rotl32(x1, 13); x1 ^= x0;
  x0 += x1; x1 = rotl32(x1, 15); x1 ^= x0;
  x0 += x1; x1 = rotl32(x1, 26); x1 ^= x0;
  x0 += x1; x1 = rotl32(x1, 6);  x1 ^= x0;
  x0 += k0; x1 += k1 + 3u;
  x0 += x1; x1 = rotl32(x1, 17); x1 ^= x0;
  x0 += x1; x1 = rotl32(x1, 29); x1 ^= x0;
  x0 += x1; x1 = rotl32(x1, 16); x1 ^= x0;
  x0 += x1; x1 = rotl32(x1, 24); x1 ^= x0;
  x0 += k1; x1 += ks2 + 4u;
  x0 += x1; x1 = rotl32(x1, 13); x1 ^= x0;
  x0 += x1; x1 = rotl32(x1, 15); x1 ^= x0;
  x0 += x1; x1 = rotl32(x1, 26); x1 ^= x0;
  x0 += x1; x1 = rotl32(x1, 6);  x1 ^= x0;
  x0 += ks2; x1 += k0 + 5u;
  o0 = x0; o1 = x1;
}

__device__ __forceinline__ bool tf_keep(uint32_t k0, uint32_t k1, uint32_t idx) {
  uint32_t o0, o1;
  tf2x32(k0, k1, 0u, idx, o0, o1);
  return ((o0 ^ o1) >> 31) == 0u;
}

// ---------------------------------------------------------------------------
// CSR build, chunk-major staging. Bucket b = dst>>7 (128 nodes). CHUNK=4096.
// staging[chunk*CHUNK + localoff(chunk,b) + i] = (dst&127)<<17 | src
// tbl[chunk*NB + b] = (localoff<<16) | count   (localoff,count < 4096)
// ---------------------------------------------------------------------------
#define CHUNK 4096
#define STASH 5120

__global__ __launch_bounds__(1024) void zero1024(uint32_t* __restrict__ p) {
  p[threadIdx.x] = 0u;
}

// Per-chunk bucket histogram -> tbl row (counts) + global bucket totals.
__global__ __launch_bounds__(256) void k1_hist(const int* __restrict__ dst,
                                               uint32_t* __restrict__ tbl,
                                               uint32_t* __restrict__ gbcnt,
                                               int E, int NB) {
  __shared__ uint32_t lc[1024];
  int tid = threadIdx.x;
  for (int i = tid; i < NB; i += 256) lc[i] = 0u;
  __syncthreads();
  int base = blockIdx.x * CHUNK;
  int end = min(base + CHUNK, E);
  for (int i = base + tid; i < end; i += 256)
    atomicAdd(&lc[((uint32_t)dst[i]) >> 7], 1u);
  __syncthreads();
  uint32_t* row = tbl + (size_t)blockIdx.x * NB;
  for (int i = tid; i < NB; i += 256) {
    uint32_t c = lc[i];
    row[i] = c;
    if (c) atomicAdd(&gbcnt[i], c);
  }
}

// Exclusive scan of gbcnt -> bbase (NB <= 1024, one block).
__global__ __launch_bounds__(1024) void k3_bscan(const uint32_t* __restrict__ gbcnt,
                                                 uint32_t* __restrict__ bbase, int NB) {
  __shared__ uint32_t s[1024];
  int i = threadIdx.x;
  uint32_t v = (i < NB) ? gbcnt[i] : 0u;
  s[i] = v;
  __syncthreads();
  for (int off = 1; off < 1024; off <<= 1) {
    uint32_t t = (i >= off) ? s[i - off] : 0u;
    __syncthreads();
    if (i >= off) s[i] += t;
    __syncthreads();
  }
  if (i < NB) bbase[i] = s[i] - v;
}

// LDS counting sort of one chunk; coalesced flush to chunk-major staging.
// Rewrites its tbl row to packed (localoff<<16)|count.
__global__ __launch_bounds__(256) void k4_bin(const int* __restrict__ src,
                                              const int* __restrict__ dst,
                                              uint32_t* __restrict__ tbl,
                                              uint32_t* __restrict__ staging,
                                              int E, int NB) {
  __shared__ uint32_t lcur[1024];
  __shared__ uint32_t ls[256];
  __shared__ uint32_t stage[CHUNK];
  int tid = threadIdx.x;
  uint32_t* row = tbl + (size_t)blockIdx.x * NB;
  // segmented exclusive scan of this row (NB <= 1024, 4 segments of 256)
  uint32_t carry = 0u;
  for (int seg = 0; seg < 1024; seg += 256) {
    int i = seg + tid;
    uint32_t v = (i < NB) ? row[i] : 0u;
    ls[tid] = v;
    __syncthreads();
    for (int off = 1; off < 256; off <<= 1) {
      uint32_t t = (tid >= off) ? ls[tid - off] : 0u;
      __syncthreads();
      if (tid >= off) ls[tid] += t;
      __syncthreads();
    }
    uint32_t excl = carry + ls[tid] - v;
    if (i < NB) {
      row[i] = (excl << 16) | v;
      lcur[i] = excl;
    }
    carry += ls[255];
    __syncthreads();
  }
  // bin into LDS
  int base = blockIdx.x * CHUNK;
  int end = min(base + CHUNK, E);
  for (int i = base + tid; i < end; i += 256) {
    uint32_t d = (uint32_t)dst[i];
    uint32_t b = d >> 7;
    uint32_t p = atomicAdd(&lcur[b], 1u);
    stage[p] = ((d & 127u) << 17) | (uint32_t)src[i];
  }
  __syncthreads();
  // coalesced flush (block-exclusive contiguous region)
  int cnt_total = end - base;
  uint32_t* outp = staging + (size_t)blockIdx.x * CHUNK;
  for (int i = tid; i < cnt_total; i += 256) outp[i] = stage[i];
}

// One block per bucket: chunk-prefix -> per-node counts -> scan -> rowp/dinv
// -> placement into esrc (bucket-owned region). Edges stashed in LDS.
__global__ __launch_bounds__(256) void k5_fin(
    const uint32_t* __restrict__ staging, const uint32_t* __restrict__ tbl,
    const uint32_t* __restrict__ bbase, uint32_t* __restrict__ rowp,
    float* __restrict__ dinv, uint32_t* __restrict__ esrc,
    int n, int E, int NBLK, int NB) {
  __shared__ uint32_t loff[1024];   // local offset of this bucket's run in chunk
  __shared__ uint32_t P[1025];      // prefix of counts over chunks
  __shared__ uint32_t ls[256];
  __shared__ uint32_t stash[STASH];
  __shared__ uint32_t lc[128];
  __shared__ uint32_t sc[128];
  __shared__ uint32_t lcur[128];
  int tid = threadIdx.x;
  int b = blockIdx.x;
  if (tid < 128) lc[tid] = 0u;
  // phase 0: load this bucket's column of tbl; scan counts -> P
  uint32_t carry = 0u;
  for (int seg = 0; seg < 1024; seg += 256) {
    int i = seg + tid;
    uint32_t packed = (i < NBLK) ? tbl[(size_t)i * NB + b] : 0u;
    uint32_t v = packed & 0xFFFFu;
    if (i < 1024) loff[i] = packed >> 16;
    ls[tid] = v;
    __syncthreads();
    for (int off = 1; off < 256; off <<= 1) {
      uint32_t t = (tid >= off) ? ls[tid - off] : 0u;
      __syncthreads();
      if (tid >= off) ls[tid] += t;
      __syncthreads();
    }
    if (i < 1024) P[i] = carry + ls[tid] - v;  // exclusive
    carry += ls[255];
    __syncthreads();
  }
  if (tid == 0) P[NBLK] = carry;
  __syncthreads();
  uint32_t total = P[NBLK];
  // phase 1: count per node (binary search chunk, read run entry, stash)
  for (uint32_t q = tid; q < total; q += 256) {
    int lo = 0, hi = NBLK;
    while (hi - lo > 1) {
      int mid = (lo + hi) >> 1;
      if (P[mid] <= q) lo = mid; else hi = mid;
    }
    uint32_t e = staging[(size_t)lo * CHUNK + loff[lo] + (q - P[lo])];
    if (q < STASH) stash[q] = e;
    atomicAdd(&lc[e >> 17], 1u);
  }
  __syncthreads();
  // phase 2: node scan -> rowp, dinv, cursors
  uint32_t myc = (tid < 128) ? lc[tid] : 0u;
  if (tid < 128) sc[tid] = myc;
  __syncthreads();
  for (int off = 1; off < 128; off <<= 1) {
    uint32_t t = (tid < 128 && tid >= off) ? sc[tid - off] : 0u;
    __syncthreads();
    if (tid < 128 && tid >= off) sc[tid] += t;
    __syncthreads();
  }
  uint32_t s = bbase[b];
  if (tid < 128) {
    uint32_t gstart = s + sc[tid] - myc;
    int node = (b << 7) + tid;
    if (node < n) {
      rowp[node] = gstart;
      dinv[node] = 1.0f / sqrtf((float)(myc + 1u));
    }
    lcur[tid] = gstart;
  }
  if (b == 0 && tid == 0) rowp[n] = (uint32_t)E;
  __syncthreads();
  // phase 3: place (stash hit or re-read)
  for (uint32_t q = tid; q < total; q += 256) {
    uint32_t e;
    if (q < STASH) {
      e = stash[q];
    } else {
      int lo = 0, hi = NBLK;
      while (hi - lo > 1) {
        int mid = (lo + hi) >> 1;
        if (P[mid] <= q) lo = mid; else hi = mid;
      }
      e = staging[(size_t)lo * CHUNK + loff[lo] + (q - P[lo])];
    }
    uint32_t pos = atomicAdd(&lcur[e >> 17], 1u);
    esrc[pos] = e & 0x1FFFFu;
  }
}

// ---------------------------------------------------------------------------
// GEMM: out[n,32] = dinv[row] * (X[n,64] @ W[64,32]).
// ---------------------------------------------------------------------------
__global__ __launch_bounds__(256) void gemm_n64_k32(
    const float* __restrict__ X, const float* __restrict__ W,
    const float* __restrict__ dinv, float* __restrict__ out, int n) {
  __shared__ float Ws[64 * 32];
  __shared__ float Xs[32 * 68];
  int tid = threadIdx.x;
  {
    const float4* Wv = (const float4*)W;
    float4* Wsv = (float4*)Ws;
    Wsv[tid] = Wv[tid];
    Wsv[tid + 256] = Wv[tid + 256];
  }
  int row0 = blockIdx.x * 32;
  {
    const float4* Xv = (const float4*)(X + (size_t)row0 * 64);
    int lim = (n - row0) * 16;
    float4 z = make_float4(0.f, 0.f, 0.f, 0.f);
    int i0 = tid, i1 = tid + 256;
    float4 v0 = (i0 < lim) ? Xv[i0] : z;
    float4 v1 = (i1 < lim) ? Xv[i1] : z;
    *(float4*)(Xs + (i0 >> 4) * 68 + ((i0 & 15) << 2)) = v0;
    *(float4*)(Xs + (i1 >> 4) * 68 + ((i1 & 15) << 2)) = v1;
  }
  __syncthreads();
  int r = tid >> 3;
  int c4 = (tid & 7) << 2;
  int row = row0 + r;
  if (row >= n) return;
  float4 acc = make_float4(0.f, 0.f, 0.f, 0.f);
#pragma unroll
  for (int k = 0; k < 64; k += 4) {
    float4 xv = *(const float4*)(Xs + r * 68 + k);
    float4 w0 = *(const float4*)(Ws + (k + 0) * 32 + c4);
    float4 w1 = *(const float4*)(Ws + (k + 1) * 32 + c4);
    float4 w2 = *(const float4*)(Ws + (k + 2) * 32 + c4);
    float4 w3 = *(const float4*)(Ws + (k + 3) * 32 + c4);
    acc.x = fmaf(xv.x, w0.x, acc.x); acc.y = fmaf(xv.x, w0.y, acc.y);
    acc.z = fmaf(xv.x, w0.z, acc.z); acc.w = fmaf(xv.x, w0.w, acc.w);
    acc.x = fmaf(xv.y, w1.x, acc.x); acc.y = fmaf(xv.y, w1.y, acc.y);
    acc.z = fmaf(xv.y, w1.z, acc.z); acc.w = fmaf(xv.y, w1.w, acc.w);
    acc.x = fmaf(xv.z, w2.x, acc.x); acc.y = fmaf(xv.z, w2.y, acc.y);
    acc.z = fmaf(xv.z, w2.z, acc.z); acc.w = fmaf(xv.z, w2.w, acc.w);
    acc.x = fmaf(xv.w, w3.x, acc.x); acc.y = fmaf(xv.w, w3.y, acc.y);
    acc.z = fmaf(xv.w, w3.z, acc.z); acc.w = fmaf(xv.w, w3.w, acc.w);
  }
  float dj = dinv[row];
  acc.x *= dj; acc.y *= dj; acc.z *= dj; acc.w *= dj;
  *(float4*)(out + (size_t)row * 32 + c4) = acc;
}

// ---------------------------------------------------------------------------
// GEMM: out[n,64] = dropout(celu(X[n,32] @ W[32,64] + b)).
// ---------------------------------------------------------------------------
__global__ __launch_bounds__(256) void gemm_k32_n64_act(
    const float* __restrict__ X, const float* __restrict__ W,
    const float* __restrict__ bias, float* __restrict__ out,
    uint32_t k0, uint32_t k1, int n) {
  __shared__ float Ws[32 * 64];
  __shared__ float Xs[16 * 36];
  int tid = threadIdx.x;
  {
    const float4* Wv = (const float4*)W;
    float4* Wsv = (float4*)Ws;
    Wsv[tid] = Wv[tid];
    Wsv[tid + 256] = Wv[tid + 256];
  }
  int row0 = blockIdx.x * 16;
  if (tid < 128) {
    const float4* Xv = (const float4*)(X + (size_t)row0 * 32);
    int lim = (n - row0) * 8;
    float4 z = make_float4(0.f, 0.f, 0.f, 0.f);
    float4 v = (tid < lim) ? Xv[tid] : z;
    *(float4*)(Xs + (tid >> 3) * 36 + ((tid & 7) << 2)) = v;
  }
  __syncthreads();
  int r = tid >> 4;
  int c4 = (tid & 15) << 2;
  int row = row0 + r;
  if (row >= n) return;
  float4 acc = make_float4(0.f, 0.f, 0.f, 0.f);
#pragma unroll
  for (int k = 0; k < 32; k += 4) {
    float4 xv = *(const float4*)(Xs + r * 36 + k);
    float4 w0 = *(const float4*)(Ws + (k + 0) * 64 + c4);
    float4 w1 = *(const float4*)(Ws + (k + 1) * 64 + c4);
    float4 w2 = *(const float4*)(Ws + (k + 2) * 64 + c4);
    float4 w3 = *(const float4*)(Ws + (k + 3) * 64 + c4);
    acc.x = fmaf(xv.x, w0.x, acc.x); acc.y = fmaf(xv.x, w0.y, acc.y);
    acc.z = fmaf(xv.x, w0.z, acc.z); acc.w = fmaf(xv.x, w0.w, acc.w);
    acc.x = fmaf(xv.y, w1.x, acc.x); acc.y = fmaf(xv.y, w1.y, acc.y);
    acc.z = fmaf(xv.y, w1.z, acc.z); acc.w = fmaf(xv.y, w1.w, acc.w);
    acc.x = fmaf(xv.z, w2.x, acc.x); acc.y = fmaf(xv.z, w2.y, acc.y);
    acc.z = fmaf(xv.z, w2.z, acc.z); acc.w = fmaf(xv.z, w2.w, acc.w);
    acc.x = fmaf(xv.w, w3.x, acc.x); acc.y = fmaf(xv.w, w3.y, acc.y);
    acc.z = fmaf(xv.w, w3.z, acc.z); acc.w = fmaf(xv.w, w3.w, acc.w);
  }
  float4 bv = *(const float4*)(bias + c4);
  float vv[4] = {acc.x + bv.x, acc.y + bv.y, acc.z + bv.z, acc.w + bv.w};
  uint32_t base = (uint32_t)row * 64u + (uint32_t)c4;
#pragma unroll
  for (int q = 0; q < 4; ++q) {
    float v = vv[q];
    v = v > 0.f ? v : expm1f(v);
    vv[q] = tf_keep(k0, k1, base + q) ? v * 2.f : 0.f;
  }
  *(float4*)(out + (size_t)row * 64 + c4) = make_float4(vv[0], vv[1], vv[2], vv[3]);
}

// ---------------------------------------------------------------------------
// Gather-reduce: 32 lanes per dst j (4 edge slots x 8 dim-chunks), float4 rows,
// shuffle reduce, lane-permute redistribution, fused epilogue.
// ---------------------------------------------------------------------------
__global__ __launch_bounds__(256) void gather_fin(
    const float* __restrict__ hs, const uint32_t* __restrict__ rowp,
    const uint32_t* __restrict__ esrc, const float* __restrict__ dinv,
    const float* __restrict__ bias, float* __restrict__ out,
    int n, int mode, uint32_t k0, uint32_t k1) {
  int gt = blockIdx.x * 256 + threadIdx.x;
  int j = gt >> 5;
  if (j >= n) return;
  int l = threadIdx.x & 31;
  int eslot = l >> 3;
  int c4 = (l & 7) << 2;
  float4 acc = make_float4(0.f, 0.f, 0.f, 0.f);
  uint32_t e1 = rowp[j + 1];
  uint32_t e = rowp[j] + (uint32_t)eslot;
  for (; e + 4 < e1; e += 8) {
    uint32_t s0 = esrc[e];
    uint32_t s1 = esrc[e + 4];
    float4 v0 = *(const float4*)(hs + ((size_t)s0 << 5) + c4);
    float4 v1 = *(const float4*)(hs + ((size_t)s1 << 5) + c4);
    acc.x += v0.x + v1.x;
    acc.y += v0.y + v1.y;
    acc.z += v0.z + v1.z;
    acc.w += v0.w + v1.w;
  }
  if (e < e1) {
    uint32_t s0 = esrc[e];
    float4 v0 = *(const float4*)(hs + ((size_t)s0 << 5) + c4);
    acc.x += v0.x; acc.y += v0.y; acc.z += v0.z; acc.w += v0.w;
  }
  acc.x += __shfl_xor(acc.x, 8);  acc.y += __shfl_xor(acc.y, 8);
  acc.z += __shfl_xor(acc.z, 8);  acc.w += __shfl_xor(acc.w, 8);
  acc.x += __shfl_xor(acc.x, 16); acc.y += __shfl_xor(acc.y, 16);
  acc.z += __shfl_xor(acc.z, 16); acc.w += __shfl_xor(acc.w, 16);
  int srcLane = (threadIdx.x & 32) | (l >> 2);
  float va = __shfl(acc.x, srcLane);
  float vb = __shfl(acc.y, srcLane);
  float vc = __shfl(acc.z, srcLane);
  float vd = __shfl(acc.w, srcLane);
  float lo = (l & 1) ? vb : va;
  float hi = (l & 1) ? vd : vc;
  float sum = (l & 2) ? hi : lo;
  sum += hs[gt];
  float dj = dinv[j];
  float v = dj * sum;
  if (mode == 1) {
    v += bias[l];
    v = v > 0.f ? v : expm1f(v);
  } else if (mode == 3) {
    v += bias[l];
    v = v > 0.f ? v : expm1f(v);
    v = tf_keep(k0, k1, (uint32_t)gt) ? v * 2.f : 0.f;
    v *= dj;
  }
  out[gt] = v;
}

// ---------------------------------------------------------------------------
extern "C" void kernel_launch(void* const* d_in, const int* in_sizes, int n_in,
                              void* d_out, int out_size, void* d_ws, size_t ws_size,
                              hipStream_t stream) {
  const float* x  = (const float*)d_in[0];
  const int*   ei = (const int*)d_in[1];
  const float* W1 = (const float*)d_in[2];
  const float* b1 = (const float*)d_in[3];
  const float* W2 = (const float*)d_in[4];
  const float* b2 = (const float*)d_in[5];
  const float* W3 = (const float*)d_in[6];
  const float* b3 = (const float*)d_in[7];
  float* out = (float*)d_out;

  const int n = in_sizes[0] / 64;
  const int E = in_sizes[1] / 2;
  const int* src = ei;
  const int* dst = ei + E;

  char* ws = (char*)d_ws;
  size_t off = 0;
  auto alloc = [&](size_t bytes) {
    void* p = ws + off;
    off = (off + bytes + 255) & ~(size_t)255;
    return p;
  };
  float*    A     = (float*)alloc((size_t)n * 32 * 4);  // aliased as tbl (CSR build)
  float*    B     = (float*)alloc((size_t)n * 32 * 4);
  float*    C     = (float*)alloc((size_t)n * 64 * 4);  // aliased as staging
  float*    dinv  = (float*)alloc((size_t)n * 4);
  uint32_t* rowp  = (uint32_t*)alloc((size_t)(n + 1) * 4);
  uint32_t* esrc  = (uint32_t*)alloc((size_t)E * 4);
  uint32_t* gbcnt = (uint32_t*)alloc(1024 * 4);
  uint32_t* bbase = (uint32_t*)alloc(1024 * 4);
  uint32_t* staging = (uint32_t*)C;   // C dead until layer 2
  uint32_t* tbl     = (uint32_t*)A;   // A dead until gemm1 (NBLK*NB*4 = 2.45MB <= 12.8MB)
  (void)ws_size; (void)n_in; (void)out_size;

  uint32_t k1a, k1b, k2a, k2b;
  tf2x32(0u, 42u, 0u, 0u, k1a, k1b);
  tf2x32(0u, 42u, 0u, 1u, k2a, k2b);

  const int NB   = (n + 127) >> 7;              // 782 buckets
  const int NBLK = (E + CHUNK - 1) / CHUNK;     // 782 chunk-blocks
  const int nv   = n * 32;
  const int gV   = (nv + 255) / 256;
  const int gG1  = (n + 31) / 32;
  const int gG2  = (n + 15) / 16;
  dim3 blk(256);

  // ---- CSR build ----
  zero1024<<<1, dim3(1024), 0, stream>>>(gbcnt);
  k1_hist<<<NBLK, blk, 0, stream>>>(dst, tbl, gbcnt, E, NB);
  k3_bscan<<<1, dim3(1024), 0, stream>>>(gbcnt, bbase, NB);
  k4_bin<<<NBLK, blk, 0, stream>>>(src, dst, tbl, staging, E, NB);
  k5_fin<<<NB, blk, 0, stream>>>(staging, tbl, bbase, rowp, dinv, esrc, n, E, NBLK, NB);

  // ---- layer 1 ----
  gemm_n64_k32<<<gG1, blk, 0, stream>>>(x, W1, dinv, A, n);
  gather_fin<<<gV, blk, 0, stream>>>(A, rowp, esrc, dinv, b1, B, n, 3, k1a, k1b);

  // ---- layer 2 ----
  gather_fin<<<gV, blk, 0, stream>>>(B, rowp, esrc, dinv, nullptr, A, n, 0, 0u, 0u);
  gemm_k32_n64_act<<<gG2, blk, 0, stream>>>(A, W2, b2, C, k2a, k2b, n);

  // ---- layer 3 ----
  gemm_n64_k32<<<gG1, blk, 0, stream>>>(C, W3, dinv, A, n);
  gather_fin<<<gV, blk, 0, stream>>>(A, rowp, esrc, dinv, b3, out, n, 1, 0u, 0u);
}

// Round 7
// 375.987 us; speedup vs baseline: 11.2157x; 1.0141x over previous
//
#include <hip/hip_runtime.h>
#include <stdint.h>
#include <stddef.h>

// ---------------------------------------------------------------------------
// JAX threefry2x32 (partitionable mode — verified: absmax 2.4e-4).
// ---------------------------------------------------------------------------
__host__ __device__ __forceinline__ uint32_t rotl32(uint32_t v, uint32_t r) {
  return (v << r) | (v >> (32u - r));
}

__host__ __device__ __forceinline__ void tf2x32(uint32_t k0, uint32_t k1,
                                                uint32_t x0, uint32_t x1,
                                                uint32_t& o0, uint32_t& o1) {
  uint32_t ks2 = k0 ^ k1 ^ 0x1BD11BDAu;
  x0 += k0; x1 += k1;
  x0 += x1; x1 = rotl32(x1, 13); x1 ^= x0;
  x0 += x1; x1 = rotl32(x1, 15); x1 ^= x0;
  x0 += x1; x1 = rotl32(x1, 26); x1 ^= x0;
  x0 += x1; x1 = rotl32(x1, 6);  x1 ^= x0;
  x0 += k1; x1 += ks2 + 1u;
  x0 += x1; x1 = rotl32(x1, 17); x1 ^= x0;
  x0 += x1; x1 = rotl32(x1, 29); x1 ^= x0;
  x0 += x1; x1 = rotl32(x1, 16); x1 ^= x0;
  x0 += x1; x1 = rotl32(x1, 24); x1 ^= x0;
  x0 += ks2; x1 += k0 + 2u;
  x0 += x1; x1 = rotl32(x1, 13); x1 ^= x0;
  x0 += x1; x1 = rotl32(x1, 15); x1 ^= x0;
  x0 += x1; x1 = rotl32(x1, 26); x1 ^= x0;
  x0 += x1; x1 = rotl32(x1, 6);  x1 ^= x0;
  x0 += k0; x1 += k1 + 3u;
  x0 += x1; x1 = rotl32(x1, 17); x1 ^= x0;
  x0 += x1; x1 = rotl32(x1, 29); x1 ^= x0;
  x0 += x1; x1 = rotl32(x1, 16); x1 ^= x0;
  x0 += x1; x1 = rotl32(x1, 24); x1 ^= x0;
  x0 += k1; x1 += ks2 + 4u;
  x0 += x1; x1 = rotl32(x1, 13); x1 ^= x0;
  x0 += x1; x1 = rotl32(x1, 15); x1 ^= x0;
  x0 += x1; x1 = rotl32(x1, 26); x1 ^= x0;
  x0 += x1; x1 = rotl32(x1, 6);  x1 ^= x0;
  x0 += ks2; x1 += k0 + 5u;
  o0 = x0; o1 = x1;
}

__device__ __forceinline__ bool tf_keep(uint32_t k0, uint32_t k1, uint32_t idx) {
  uint32_t o0, o1;
  tf2x32(k0, k1, 0u, idx, o0, o1);
  return ((o0 ^ o1) >> 31) == 0u;
}

// ---------------------------------------------------------------------------
// CSR build, chunk-major staging. Bucket b = dst>>7 (128 nodes). CHUNK=4096.
// staging[chunk*CHUNK + localoff(chunk,b) + i] = (dst&127)<<17 | src
// tbl[chunk*NB + b] = (localoff<<16) | count
// ---------------------------------------------------------------------------
#define CHUNK 4096
#define STASH 5120

__global__ __launch_bounds__(1024) void zero1024(uint32_t* __restrict__ p) {
  p[threadIdx.x] = 0u;
}

// Fused: per-chunk histogram + scan + gbcnt accumulation + LDS counting sort
// + coalesced flush. (k1_hist merged in — one pass over dst/src.)
__global__ __launch_bounds__(256) void k4_binhist(const int* __restrict__ src,
                                                  const int* __restrict__ dst,
                                                  uint32_t* __restrict__ tbl,
                                                  uint32_t* __restrict__ gbcnt,
                                                  uint32_t* __restrict__ staging,
                                                  int E, int NB) {
  __shared__ uint32_t lcur[1024];
  __shared__ uint32_t ls[256];
  __shared__ uint32_t stage[CHUNK];
  int tid = threadIdx.x;
  for (int i = tid; i < NB; i += 256) lcur[i] = 0u;
  __syncthreads();
  int base = blockIdx.x * CHUNK;
  int end = min(base + CHUNK, E);
  // stage edges in registers (<=16/thread), histogram
  uint32_t dv[16], sv[16];
  int m = 0;
  for (int i = base + tid; i < end; i += 256) {
    dv[m] = (uint32_t)dst[i];
    sv[m] = (uint32_t)src[i];
    ++m;
  }
  for (int q = 0; q < m; ++q) atomicAdd(&lcur[dv[q] >> 7], 1u);
  __syncthreads();
  // segmented exclusive scan; write packed tbl row; accumulate bucket totals
  uint32_t carry = 0u;
  for (int seg = 0; seg < 1024; seg += 256) {
    int i = seg + tid;
    uint32_t v = (i < NB) ? lcur[i] : 0u;
    ls[tid] = v;
    __syncthreads();
    for (int off = 1; off < 256; off <<= 1) {
      uint32_t t = (tid >= off) ? ls[tid - off] : 0u;
      __syncthreads();
      if (tid >= off) ls[tid] += t;
      __syncthreads();
    }
    uint32_t excl = carry + ls[tid] - v;
    if (i < NB) {
      tbl[(size_t)blockIdx.x * NB + i] = (excl << 16) | v;
      if (v) atomicAdd(&gbcnt[i], v);
      lcur[i] = excl;  // cursor for the sort
    }
    carry += ls[255];
    __syncthreads();
  }
  // bin into LDS, then coalesced flush to block-owned region
  for (int q = 0; q < m; ++q) {
    uint32_t d = dv[q];
    uint32_t p = atomicAdd(&lcur[d >> 7], 1u);
    stage[p] = ((d & 127u) << 17) | sv[q];
  }
  __syncthreads();
  int cnt_total = end - base;
  uint32_t* outp = staging + (size_t)blockIdx.x * CHUNK;
  for (int i = tid; i < cnt_total; i += 256) outp[i] = stage[i];
}

// Exclusive scan of gbcnt -> bbase (NB <= 1024, one block).
__global__ __launch_bounds__(1024) void k3_bscan(const uint32_t* __restrict__ gbcnt,
                                                 uint32_t* __restrict__ bbase, int NB) {
  __shared__ uint32_t s[1024];
  int i = threadIdx.x;
  uint32_t v = (i < NB) ? gbcnt[i] : 0u;
  s[i] = v;
  __syncthreads();
  for (int off = 1; off < 1024; off <<= 1) {
    uint32_t t = (i >= off) ? s[i - off] : 0u;
    __syncthreads();
    if (i >= off) s[i] += t;
    __syncthreads();
  }
  if (i < NB) bbase[i] = s[i] - v;
}

// One block per bucket: chunk-run walk (no binary search) -> stash + counts
// -> node scan -> rowp/dinv -> placement from stash (bucket-owned esrc region).
__global__ __launch_bounds__(256) void k5_fin(
    const uint32_t* __restrict__ staging, const uint32_t* __restrict__ tbl,
    const uint32_t* __restrict__ bbase, uint32_t* __restrict__ rowp,
    float* __restrict__ dinv, uint32_t* __restrict__ esrc,
    int n, int E, int NBLK, int NB) {
  __shared__ uint32_t lpak[1024];
  __shared__ uint32_t P[1025];
  __shared__ uint32_t ls[256];
  __shared__ uint32_t stash[STASH];
  __shared__ uint32_t lc[128];
  __shared__ uint32_t sc[128];
  __shared__ uint32_t lcur[128];
  int tid = threadIdx.x;
  int b = blockIdx.x;
  if (tid < 128) lc[tid] = 0u;
  // load column b of tbl; scan counts -> P (exclusive prefix over chunks)
  uint32_t carry = 0u;
  for (int seg = 0; seg < 1024; seg += 256) {
    int i = seg + tid;
    uint32_t packed = (i < NBLK) ? tbl[(size_t)i * NB + b] : 0u;
    lpak[i] = packed;
    uint32_t v = packed & 0xFFFFu;
    ls[tid] = v;
    __syncthreads();
    for (int off = 1; off < 256; off <<= 1) {
      uint32_t t = (tid >= off) ? ls[tid - off] : 0u;
      __syncthreads();
      if (tid >= off) ls[tid] += t;
      __syncthreads();
    }
    P[i] = carry + ls[tid] - v;
    carry += ls[255];
    __syncthreads();
  }
  if (tid == 0) P[NBLK] = carry;
  __syncthreads();
  uint32_t total = P[NBLK];
  // phase 1: walk chunk runs, stash edges, count per node
  for (int i = tid; i < NBLK; i += 256) {
    uint32_t packed = lpak[i];
    uint32_t cnt = packed & 0xFFFFu;
    uint32_t loff = packed >> 16;
    uint32_t p = P[i];
    const uint32_t* run = staging + (size_t)i * CHUNK + loff;
    for (uint32_t t2 = 0; t2 < cnt; ++t2) {
      uint32_t e = run[t2];
      uint32_t q = p + t2;
      if (q < STASH) stash[q] = e;
      atomicAdd(&lc[e >> 17], 1u);
    }
  }
  __syncthreads();
  // phase 2: node scan -> rowp, dinv, cursors
  uint32_t myc = (tid < 128) ? lc[tid] : 0u;
  if (tid < 128) sc[tid] = myc;
  __syncthreads();
  for (int off = 1; off < 128; off <<= 1) {
    uint32_t t = (tid < 128 && tid >= off) ? sc[tid - off] : 0u;
    __syncthreads();
    if (tid < 128 && tid >= off) sc[tid] += t;
    __syncthreads();
  }
  uint32_t s = bbase[b];
  if (tid < 128) {
    uint32_t gstart = s + sc[tid] - myc;
    int node = (b << 7) + tid;
    if (node < n) {
      rowp[node] = gstart;
      dinv[node] = 1.0f / sqrtf((float)(myc + 1u));
    }
    lcur[tid] = gstart;
  }
  if (b == 0 && tid == 0) rowp[n] = (uint32_t)E;
  __syncthreads();
  // phase 3: place from stash; rare overflow re-walks chunk runs
  uint32_t lim = total < (uint32_t)STASH ? total : (uint32_t)STASH;
  for (uint32_t q = tid; q < lim; q += 256) {
    uint32_t e = stash[q];
    uint32_t pos = atomicAdd(&lcur[e >> 17], 1u);
    esrc[pos] = e & 0x1FFFFu;
  }
  if (total > (uint32_t)STASH) {
    for (int i = tid; i < NBLK; i += 256) {
      uint32_t packed = lpak[i];
      uint32_t cnt = packed & 0xFFFFu;
      uint32_t loff = packed >> 16;
      uint32_t p = P[i];
      const uint32_t* run = staging + (size_t)i * CHUNK + loff;
      for (uint32_t t2 = 0; t2 < cnt; ++t2) {
        uint32_t q = p + t2;
        if (q >= (uint32_t)STASH) {
          uint32_t e = run[t2];
          uint32_t pos = atomicAdd(&lcur[e >> 17], 1u);
          esrc[pos] = e & 0x1FFFFu;
        }
      }
    }
  }
}

// ---------------------------------------------------------------------------
// GEMM: out[n,32] = dinv[row] * (X[n,64] @ W[64,32]).
// ---------------------------------------------------------------------------
__global__ __launch_bounds__(256) void gemm_n64_k32(
    const float* __restrict__ X, const float* __restrict__ W,
    const float* __restrict__ dinv, float* __restrict__ out, int n) {
  __shared__ float Ws[64 * 32];
  __shared__ float Xs[32 * 68];
  int tid = threadIdx.x;
  {
    const float4* Wv = (const float4*)W;
    float4* Wsv = (float4*)Ws;
    Wsv[tid] = Wv[tid];
    Wsv[tid + 256] = Wv[tid + 256];
  }
  int row0 = blockIdx.x * 32;
  {
    const float4* Xv = (const float4*)(X + (size_t)row0 * 64);
    int lim = (n - row0) * 16;
    float4 z = make_float4(0.f, 0.f, 0.f, 0.f);
    int i0 = tid, i1 = tid + 256;
    float4 v0 = (i0 < lim) ? Xv[i0] : z;
    float4 v1 = (i1 < lim) ? Xv[i1] : z;
    *(float4*)(Xs + (i0 >> 4) * 68 + ((i0 & 15) << 2)) = v0;
    *(float4*)(Xs + (i1 >> 4) * 68 + ((i1 & 15) << 2)) = v1;
  }
  __syncthreads();
  int r = tid >> 3;
  int c4 = (tid & 7) << 2;
  int row = row0 + r;
  if (row >= n) return;
  float4 acc = make_float4(0.f, 0.f, 0.f, 0.f);
#pragma unroll
  for (int k = 0; k < 64; k += 4) {
    float4 xv = *(const float4*)(Xs + r * 68 + k);
    float4 w0 = *(const float4*)(Ws + (k + 0) * 32 + c4);
    float4 w1 = *(const float4*)(Ws + (k + 1) * 32 + c4);
    float4 w2 = *(const float4*)(Ws + (k + 2) * 32 + c4);
    float4 w3 = *(const float4*)(Ws + (k + 3) * 32 + c4);
    acc.x = fmaf(xv.x, w0.x, acc.x); acc.y = fmaf(xv.x, w0.y, acc.y);
    acc.z = fmaf(xv.x, w0.z, acc.z); acc.w = fmaf(xv.x, w0.w, acc.w);
    acc.x = fmaf(xv.y, w1.x, acc.x); acc.y = fmaf(xv.y, w1.y, acc.y);
    acc.z = fmaf(xv.y, w1.z, acc.z); acc.w = fmaf(xv.y, w1.w, acc.w);
    acc.x = fmaf(xv.z, w2.x, acc.x); acc.y = fmaf(xv.z, w2.y, acc.y);
    acc.z = fmaf(xv.z, w2.z, acc.z); acc.w = fmaf(xv.z, w2.w, acc.w);
    acc.x = fmaf(xv.w, w3.x, acc.x); acc.y = fmaf(xv.w, w3.y, acc.y);
    acc.z = fmaf(xv.w, w3.z, acc.z); acc.w = fmaf(xv.w, w3.w, acc.w);
  }
  float dj = dinv[row];
  acc.x *= dj; acc.y *= dj; acc.z *= dj; acc.w *= dj;
  *(float4*)(out + (size_t)row * 32 + c4) = acc;
}

// ---------------------------------------------------------------------------
// GEMM: out[n,64] = dropout(celu(X[n,32] @ W[32,64] + b)).
// ---------------------------------------------------------------------------
__global__ __launch_bounds__(256) void gemm_k32_n64_act(
    const float* __restrict__ X, const float* __restrict__ W,
    const float* __restrict__ bias, float* __restrict__ out,
    uint32_t k0, uint32_t k1, int n) {
  __shared__ float Ws[32 * 64];
  __shared__ float Xs[16 * 36];
  int tid = threadIdx.x;
  {
    const float4* Wv = (const float4*)W;
    float4* Wsv = (float4*)Ws;
    Wsv[tid] = Wv[tid];
    Wsv[tid + 256] = Wv[tid + 256];
  }
  int row0 = blockIdx.x * 16;
  if (tid < 128) {
    const float4* Xv = (const float4*)(X + (size_t)row0 * 32);
    int lim = (n - row0) * 8;
    float4 z = make_float4(0.f, 0.f, 0.f, 0.f);
    float4 v = (tid < lim) ? Xv[tid] : z;
    *(float4*)(Xs + (tid >> 3) * 36 + ((tid & 7) << 2)) = v;
  }
  __syncthreads();
  int r = tid >> 4;
  int c4 = (tid & 15) << 2;
  int row = row0 + r;
  if (row >= n) return;
  float4 acc = make_float4(0.f, 0.f, 0.f, 0.f);
#pragma unroll
  for (int k = 0; k < 32; k += 4) {
    float4 xv = *(const float4*)(Xs + r * 36 + k);
    float4 w0 = *(const float4*)(Ws + (k + 0) * 64 + c4);
    float4 w1 = *(const float4*)(Ws + (k + 1) * 64 + c4);
    float4 w2 = *(const float4*)(Ws + (k + 2) * 64 + c4);
    float4 w3 = *(const float4*)(Ws + (k + 3) * 64 + c4);
    acc.x = fmaf(xv.x, w0.x, acc.x); acc.y = fmaf(xv.x, w0.y, acc.y);
    acc.z = fmaf(xv.x, w0.z, acc.z); acc.w = fmaf(xv.x, w0.w, acc.w);
    acc.x = fmaf(xv.y, w1.x, acc.x); acc.y = fmaf(xv.y, w1.y, acc.y);
    acc.z = fmaf(xv.y, w1.z, acc.z); acc.w = fmaf(xv.y, w1.w, acc.w);
    acc.x = fmaf(xv.z, w2.x, acc.x); acc.y = fmaf(xv.z, w2.y, acc.y);
    acc.z = fmaf(xv.z, w2.z, acc.z); acc.w = fmaf(xv.z, w2.w, acc.w);
    acc.x = fmaf(xv.w, w3.x, acc.x); acc.y = fmaf(xv.w, w3.y, acc.y);
    acc.z = fmaf(xv.w, w3.z, acc.z); acc.w = fmaf(xv.w, w3.w, acc.w);
  }
  float4 bv = *(const float4*)(bias + c4);
  float vv[4] = {acc.x + bv.x, acc.y + bv.y, acc.z + bv.z, acc.w + bv.w};
  uint32_t base = (uint32_t)row * 64u + (uint32_t)c4;
#pragma unroll
  for (int q = 0; q < 4; ++q) {
    float v = vv[q];
    v = v > 0.f ? v : expm1f(v);
    vv[q] = tf_keep(k0, k1, base + q) ? v * 2.f : 0.f;
  }
  *(float4*)(out + (size_t)row * 64 + c4) = make_float4(vv[0], vv[1], vv[2], vv[3]);
}

// ---------------------------------------------------------------------------
// Gather-reduce v2: 32 lanes per dst j. One coalesced esrc load covers a
// 32-edge tile; per-edge src index delivered via ds_bpermute shuffle (no
// redundant scalar loads, 8 independent row loads in flight per tile).
// ---------------------------------------------------------------------------
__global__ __launch_bounds__(256) void gather_fin(
    const float* __restrict__ hs, const uint32_t* __restrict__ rowp,
    const uint32_t* __restrict__ esrc, const float* __restrict__ dinv,
    const float* __restrict__ bias, float* __restrict__ out,
    int n, int mode, uint32_t k0, uint32_t k1) {
  int gt = blockIdx.x * 256 + threadIdx.x;
  int j = gt >> 5;
  if (j >= n) return;
  int l = threadIdx.x & 31;
  int eslot = l >> 3;
  int c4 = (l & 7) << 2;
  float4 acc = make_float4(0.f, 0.f, 0.f, 0.f);
  uint32_t e0 = rowp[j], e1 = rowp[j + 1];
  uint32_t deg = e1 - e0;
  uint32_t base = 0;
  for (; base + 32 <= deg; base += 32) {
    uint32_t idx = esrc[e0 + base + (uint32_t)l];  // 128 B coalesced, 32 edges
#pragma unroll
    for (int k = 0; k < 32; k += 4) {
      uint32_t s = (uint32_t)__shfl((int)idx, k + eslot, 32);
      const float4 v = *(const float4*)(hs + ((size_t)s << 5) + c4);
      acc.x += v.x; acc.y += v.y; acc.z += v.z; acc.w += v.w;
    }
  }
  if (base < deg) {
    uint32_t rem = deg - base;  // 1..31
    uint32_t li = (uint32_t)l < rem ? (uint32_t)l : rem - 1u;
    uint32_t idx = esrc[e0 + base + li];
    for (uint32_t k = 0; k < rem; k += 4) {
      uint32_t kk = k + (uint32_t)eslot;
      uint32_t ks = kk < rem ? kk : rem - 1u;
      uint32_t s = (uint32_t)__shfl((int)idx, (int)ks, 32);
      if (kk < rem) {
        const float4 v = *(const float4*)(hs + ((size_t)s << 5) + c4);
        acc.x += v.x; acc.y += v.y; acc.z += v.z; acc.w += v.w;
      }
    }
  }
  acc.x += __shfl_xor(acc.x, 8);  acc.y += __shfl_xor(acc.y, 8);
  acc.z += __shfl_xor(acc.z, 8);  acc.w += __shfl_xor(acc.w, 8);
  acc.x += __shfl_xor(acc.x, 16); acc.y += __shfl_xor(acc.y, 16);
  acc.z += __shfl_xor(acc.z, 16); acc.w += __shfl_xor(acc.w, 16);
  int srcLane = (threadIdx.x & 32) | (l >> 2);
  float va = __shfl(acc.x, srcLane);
  float vb = __shfl(acc.y, srcLane);
  float vc = __shfl(acc.z, srcLane);
  float vd = __shfl(acc.w, srcLane);
  float lo = (l & 1) ? vb : va;
  float hi = (l & 1) ? vd : vc;
  float sum = (l & 2) ? hi : lo;
  sum += hs[gt];  // self-loop (already dinv[src]-scaled)
  float dj = dinv[j];
  float v = dj * sum;
  if (mode == 1) {
    v += bias[l];
    v = v > 0.f ? v : expm1f(v);
  } else if (mode == 3) {
    v += bias[l];
    v = v > 0.f ? v : expm1f(v);
    v = tf_keep(k0, k1, (uint32_t)gt) ? v * 2.f : 0.f;
    v *= dj;
  }
  out[gt] = v;
}

// ---------------------------------------------------------------------------
extern "C" void kernel_launch(void* const* d_in, const int* in_sizes, int n_in,
                              void* d_out, int out_size, void* d_ws, size_t ws_size,
                              hipStream_t stream) {
  const float* x  = (const float*)d_in[0];
  const int*   ei = (const int*)d_in[1];
  const float* W1 = (const float*)d_in[2];
  const float* b1 = (const float*)d_in[3];
  const float* W2 = (const float*)d_in[4];
  const float* b2 = (const float*)d_in[5];
  const float* W3 = (const float*)d_in[6];
  const float* b3 = (const float*)d_in[7];
  float* out = (float*)d_out;

  const int n = in_sizes[0] / 64;
  const int E = in_sizes[1] / 2;
  const int* src = ei;
  const int* dst = ei + E;

  char* ws = (char*)d_ws;
  size_t off = 0;
  auto alloc = [&](size_t bytes) {
    void* p = ws + off;
    off = (off + bytes + 255) & ~(size_t)255;
    return p;
  };
  float*    A     = (float*)alloc((size_t)n * 32 * 4);  // aliased as tbl (CSR build)
  float*    B     = (float*)alloc((size_t)n * 32 * 4);
  float*    C     = (float*)alloc((size_t)n * 64 * 4);  // aliased as staging
  float*    dinv  = (float*)alloc((size_t)n * 4);
  uint32_t* rowp  = (uint32_t*)alloc((size_t)(n + 1) * 4);
  uint32_t* esrc  = (uint32_t*)alloc((size_t)E * 4);
  uint32_t* gbcnt = (uint32_t*)alloc(1024 * 4);
  uint32_t* bbase = (uint32_t*)alloc(1024 * 4);
  uint32_t* staging = (uint32_t*)C;   // C dead until layer 2
  uint32_t* tbl     = (uint32_t*)A;   // A dead until gemm1
  (void)ws_size; (void)n_in; (void)out_size;

  uint32_t k1a, k1b, k2a, k2b;
  tf2x32(0u, 42u, 0u, 0u, k1a, k1b);
  tf2x32(0u, 42u, 0u, 1u, k2a, k2b);

  const int NB   = (n + 127) >> 7;              // 782 buckets
  const int NBLK = (E + CHUNK - 1) / CHUNK;     // 782 chunk-blocks
  const int nv   = n * 32;
  const int gV   = (nv + 255) / 256;
  const int gG1  = (n + 31) / 32;
  const int gG2  = (n + 15) / 16;
  dim3 blk(256);

  // ---- CSR build (3 kernels) ----
  zero1024<<<1, dim3(1024), 0, stream>>>(gbcnt);
  k4_binhist<<<NBLK, blk, 0, stream>>>(src, dst, tbl, gbcnt, staging, E, NB);
  k3_bscan<<<1, dim3(1024), 0, stream>>>(gbcnt, bbase, NB);
  k5_fin<<<NB, blk, 0, stream>>>(staging, tbl, bbase, rowp, dinv, esrc, n, E, NBLK, NB);

  // ---- layer 1 ----
  gemm_n64_k32<<<gG1, blk, 0, stream>>>(x, W1, dinv, A, n);
  gather_fin<<<gV, blk, 0, stream>>>(A, rowp, esrc, dinv, b1, B, n, 3, k1a, k1b);

  // ---- layer 2 ----
  gather_fin<<<gV, blk, 0, stream>>>(B, rowp, esrc, dinv, nullptr, A, n, 0, 0u, 0u);
  gemm_k32_n64_act<<<gG2, blk, 0, stream>>>(A, W2, b2, C, k2a, k2b, n);

  // ---- layer 3 ----
  gemm_n64_k32<<<gG1, blk, 0, stream>>>(C, W3, dinv, A, n);
  gather_fin<<<gV, blk, 0, stream>>>(A, rowp, esrc, dinv, b3, out, n, 1, 0u, 0u);
}

// Round 8
// 347.858 us; speedup vs baseline: 12.1227x; 1.0809x over previous
//
#include <hip/hip_runtime.h>
#include <stdint.h>
#include <stddef.h>

typedef _Float16 half_t;
typedef _Float16 half4 __attribute__((ext_vector_type(4)));

// ---------------------------------------------------------------------------
// JAX threefry2x32 (partitionable mode — verified: absmax 2.4e-4).
// ---------------------------------------------------------------------------
__host__ __device__ __forceinline__ uint32_t rotl32(uint32_t v, uint32_t r) {
  return (v << r) | (v >> (32u - r));
}

__host__ __device__ __forceinline__ void tf2x32(uint32_t k0, uint32_t k1,
                                                uint32_t x0, uint32_t x1,
                                                uint32_t& o0, uint32_t& o1) {
  uint32_t ks2 = k0 ^ k1 ^ 0x1BD11BDAu;
  x0 += k0; x1 += k1;
  x0 += x1; x1 = rotl32(x1, 13); x1 ^= x0;
  x0 += x1; x1 = rotl32(x1, 15); x1 ^= x0;
  x0 += x1; x1 = rotl32(x1, 26); x1 ^= x0;
  x0 += x1; x1 = rotl32(x1, 6);  x1 ^= x0;
  x0 += k1; x1 += ks2 + 1u;
  x0 += x1; x1 = rotl32(x1, 17); x1 ^= x0;
  x0 += x1; x1 = rotl32(x1, 29); x1 ^= x0;
  x0 += x1; x1 = rotl32(x1, 16); x1 ^= x0;
  x0 += x1; x1 = rotl32(x1, 24); x1 ^= x0;
  x0 += ks2; x1 += k0 + 2u;
  x0 += x1; x1 = rotl32(x1, 13); x1 ^= x0;
  x0 += x1; x1 = rotl32(x1, 15); x1 ^= x0;
  x0 += x1; x1 = rotl32(x1, 26); x1 ^= x0;
  x0 += x1; x1 = rotl32(x1, 6);  x1 ^= x0;
  x0 += k0; x1 += k1 + 3u;
  x0 += x1; x1 = rotl32(x1, 17); x1 ^= x0;
  x0 += x1; x1 = rotl32(x1, 29); x1 ^= x0;
  x0 += x1; x1 = rotl32(x1, 16); x1 ^= x0;
  x0 += x1; x1 = rotl32(x1, 24); x1 ^= x0;
  x0 += k1; x1 += ks2 + 4u;
  x0 += x1; x1 = rotl32(x1, 13); x1 ^= x0;
  x0 += x1; x1 = rotl32(x1, 15); x1 ^= x0;
  x0 += x1; x1 = rotl32(x1, 26); x1 ^= x0;
  x0 += x1; x1 = rotl32(x1, 6);  x1 ^= x0;
  x0 += ks2; x1 += k0 + 5u;
  o0 = x0; o1 = x1;
}

__device__ __forceinline__ bool tf_keep(uint32_t k0, uint32_t k1, uint32_t idx) {
  uint32_t o0, o1;
  tf2x32(k0, k1, 0u, idx, o0, o1);
  return ((o0 ^ o1) >> 31) == 0u;
}

// ---------------------------------------------------------------------------
// CSR build, chunk-major staging (unchanged from round 7).
// ---------------------------------------------------------------------------
#define CHUNK 4096
#define STASH 5120

__global__ __launch_bounds__(1024) void zero1024(uint32_t* __restrict__ p) {
  p[threadIdx.x] = 0u;
}

__global__ __launch_bounds__(256) void k4_binhist(const int* __restrict__ src,
                                                  const int* __restrict__ dst,
                                                  uint32_t* __restrict__ tbl,
                                                  uint32_t* __restrict__ gbcnt,
                                                  uint32_t* __restrict__ staging,
                                                  int E, int NB) {
  __shared__ uint32_t lcur[1024];
  __shared__ uint32_t ls[256];
  __shared__ uint32_t stage[CHUNK];
  int tid = threadIdx.x;
  for (int i = tid; i < NB; i += 256) lcur[i] = 0u;
  __syncthreads();
  int base = blockIdx.x * CHUNK;
  int end = min(base + CHUNK, E);
  uint32_t dv[16], sv[16];
  int m = 0;
  for (int i = base + tid; i < end; i += 256) {
    dv[m] = (uint32_t)dst[i];
    sv[m] = (uint32_t)src[i];
    ++m;
  }
  for (int q = 0; q < m; ++q) atomicAdd(&lcur[dv[q] >> 7], 1u);
  __syncthreads();
  uint32_t carry = 0u;
  for (int seg = 0; seg < 1024; seg += 256) {
    int i = seg + tid;
    uint32_t v = (i < NB) ? lcur[i] : 0u;
    ls[tid] = v;
    __syncthreads();
    for (int off = 1; off < 256; off <<= 1) {
      uint32_t t = (tid >= off) ? ls[tid - off] : 0u;
      __syncthreads();
      if (tid >= off) ls[tid] += t;
      __syncthreads();
    }
    uint32_t excl = carry + ls[tid] - v;
    if (i < NB) {
      tbl[(size_t)blockIdx.x * NB + i] = (excl << 16) | v;
      if (v) atomicAdd(&gbcnt[i], v);
      lcur[i] = excl;
    }
    carry += ls[255];
    __syncthreads();
  }
  for (int q = 0; q < m; ++q) {
    uint32_t d = dv[q];
    uint32_t p = atomicAdd(&lcur[d >> 7], 1u);
    stage[p] = ((d & 127u) << 17) | sv[q];
  }
  __syncthreads();
  int cnt_total = end - base;
  uint32_t* outp = staging + (size_t)blockIdx.x * CHUNK;
  for (int i = tid; i < cnt_total; i += 256) outp[i] = stage[i];
}

__global__ __launch_bounds__(1024) void k3_bscan(const uint32_t* __restrict__ gbcnt,
                                                 uint32_t* __restrict__ bbase, int NB) {
  __shared__ uint32_t s[1024];
  int i = threadIdx.x;
  uint32_t v = (i < NB) ? gbcnt[i] : 0u;
  s[i] = v;
  __syncthreads();
  for (int off = 1; off < 1024; off <<= 1) {
    uint32_t t = (i >= off) ? s[i - off] : 0u;
    __syncthreads();
    if (i >= off) s[i] += t;
    __syncthreads();
  }
  if (i < NB) bbase[i] = s[i] - v;
}

__global__ __launch_bounds__(256) void k5_fin(
    const uint32_t* __restrict__ staging, const uint32_t* __restrict__ tbl,
    const uint32_t* __restrict__ bbase, uint32_t* __restrict__ rowp,
    float* __restrict__ dinv, uint32_t* __restrict__ esrc,
    int n, int E, int NBLK, int NB) {
  __shared__ uint32_t lpak[1024];
  __shared__ uint32_t P[1025];
  __shared__ uint32_t ls[256];
  __shared__ uint32_t stash[STASH];
  __shared__ uint32_t lc[128];
  __shared__ uint32_t sc[128];
  __shared__ uint32_t lcur[128];
  int tid = threadIdx.x;
  int b = blockIdx.x;
  if (tid < 128) lc[tid] = 0u;
  uint32_t carry = 0u;
  for (int seg = 0; seg < 1024; seg += 256) {
    int i = seg + tid;
    uint32_t packed = (i < NBLK) ? tbl[(size_t)i * NB + b] : 0u;
    lpak[i] = packed;
    uint32_t v = packed & 0xFFFFu;
    ls[tid] = v;
    __syncthreads();
    for (int off = 1; off < 256; off <<= 1) {
      uint32_t t = (tid >= off) ? ls[tid - off] : 0u;
      __syncthreads();
      if (tid >= off) ls[tid] += t;
      __syncthreads();
    }
    P[i] = carry + ls[tid] - v;
    carry += ls[255];
    __syncthreads();
  }
  if (tid == 0) P[NBLK] = carry;
  __syncthreads();
  uint32_t total = P[NBLK];
  for (int i = tid; i < NBLK; i += 256) {
    uint32_t packed = lpak[i];
    uint32_t cnt = packed & 0xFFFFu;
    uint32_t loff = packed >> 16;
    uint32_t p = P[i];
    const uint32_t* run = staging + (size_t)i * CHUNK + loff;
    for (uint32_t t2 = 0; t2 < cnt; ++t2) {
      uint32_t e = run[t2];
      uint32_t q = p + t2;
      if (q < STASH) stash[q] = e;
      atomicAdd(&lc[e >> 17], 1u);
    }
  }
  __syncthreads();
  uint32_t myc = (tid < 128) ? lc[tid] : 0u;
  if (tid < 128) sc[tid] = myc;
  __syncthreads();
  for (int off = 1; off < 128; off <<= 1) {
    uint32_t t = (tid < 128 && tid >= off) ? sc[tid - off] : 0u;
    __syncthreads();
    if (tid < 128 && tid >= off) sc[tid] += t;
    __syncthreads();
  }
  uint32_t s = bbase[b];
  if (tid < 128) {
    uint32_t gstart = s + sc[tid] - myc;
    int node = (b << 7) + tid;
    if (node < n) {
      rowp[node] = gstart;
      dinv[node] = 1.0f / sqrtf((float)(myc + 1u));
    }
    lcur[tid] = gstart;
  }
  if (b == 0 && tid == 0) rowp[n] = (uint32_t)E;
  __syncthreads();
  uint32_t lim = total < (uint32_t)STASH ? total : (uint32_t)STASH;
  for (uint32_t q = tid; q < lim; q += 256) {
    uint32_t e = stash[q];
    uint32_t pos = atomicAdd(&lcur[e >> 17], 1u);
    esrc[pos] = e & 0x1FFFFu;
  }
  if (total > (uint32_t)STASH) {
    for (int i = tid; i < NBLK; i += 256) {
      uint32_t packed = lpak[i];
      uint32_t cnt = packed & 0xFFFFu;
      uint32_t loff = packed >> 16;
      uint32_t p = P[i];
      const uint32_t* run = staging + (size_t)i * CHUNK + loff;
      for (uint32_t t2 = 0; t2 < cnt; ++t2) {
        uint32_t q = p + t2;
        if (q >= (uint32_t)STASH) {
          uint32_t e = run[t2];
          uint32_t pos = atomicAdd(&lcur[e >> 17], 1u);
          esrc[pos] = e & 0x1FFFFu;
        }
      }
    }
  }
}

// ---------------------------------------------------------------------------
// GEMM: out16[n,32] = fp16( dinv[row] * (X[n,64] @ W[64,32]) ).
// ---------------------------------------------------------------------------
__global__ __launch_bounds__(256) void gemm_n64_k32(
    const float* __restrict__ X, const float* __restrict__ W,
    const float* __restrict__ dinv, half_t* __restrict__ out16, int n) {
  __shared__ float Ws[64 * 32];
  __shared__ float Xs[32 * 68];
  int tid = threadIdx.x;
  {
    const float4* Wv = (const float4*)W;
    float4* Wsv = (float4*)Ws;
    Wsv[tid] = Wv[tid];
    Wsv[tid + 256] = Wv[tid + 256];
  }
  int row0 = blockIdx.x * 32;
  {
    const float4* Xv = (const float4*)(X + (size_t)row0 * 64);
    int lim = (n - row0) * 16;
    float4 z = make_float4(0.f, 0.f, 0.f, 0.f);
    int i0 = tid, i1 = tid + 256;
    float4 v0 = (i0 < lim) ? Xv[i0] : z;
    float4 v1 = (i1 < lim) ? Xv[i1] : z;
    *(float4*)(Xs + (i0 >> 4) * 68 + ((i0 & 15) << 2)) = v0;
    *(float4*)(Xs + (i1 >> 4) * 68 + ((i1 & 15) << 2)) = v1;
  }
  __syncthreads();
  int r = tid >> 3;
  int c4 = (tid & 7) << 2;
  int row = row0 + r;
  if (row >= n) return;
  float4 acc = make_float4(0.f, 0.f, 0.f, 0.f);
#pragma unroll
  for (int k = 0; k < 64; k += 4) {
    float4 xv = *(const float4*)(Xs + r * 68 + k);
    float4 w0 = *(const float4*)(Ws + (k + 0) * 32 + c4);
    float4 w1 = *(const float4*)(Ws + (k + 1) * 32 + c4);
    float4 w2 = *(const float4*)(Ws + (k + 2) * 32 + c4);
    float4 w3 = *(const float4*)(Ws + (k + 3) * 32 + c4);
    acc.x = fmaf(xv.x, w0.x, acc.x); acc.y = fmaf(xv.x, w0.y, acc.y);
    acc.z = fmaf(xv.x, w0.z, acc.z); acc.w = fmaf(xv.x, w0.w, acc.w);
    acc.x = fmaf(xv.y, w1.x, acc.x); acc.y = fmaf(xv.y, w1.y, acc.y);
    acc.z = fmaf(xv.y, w1.z, acc.z); acc.w = fmaf(xv.y, w1.w, acc.w);
    acc.x = fmaf(xv.z, w2.x, acc.x); acc.y = fmaf(xv.z, w2.y, acc.y);
    acc.z = fmaf(xv.z, w2.z, acc.z); acc.w = fmaf(xv.z, w2.w, acc.w);
    acc.x = fmaf(xv.w, w3.x, acc.x); acc.y = fmaf(xv.w, w3.y, acc.y);
    acc.z = fmaf(xv.w, w3.z, acc.z); acc.w = fmaf(xv.w, w3.w, acc.w);
  }
  float dj = dinv[row];
  half4 h;
  h.x = (half_t)(acc.x * dj); h.y = (half_t)(acc.y * dj);
  h.z = (half_t)(acc.z * dj); h.w = (half_t)(acc.w * dj);
  *(half4*)(out16 + (size_t)row * 32 + c4) = h;
}

// ---------------------------------------------------------------------------
// GEMM: out[n,64] = dropout(celu(X[n,32] @ W[32,64] + b))  (fp32 in/out).
// ---------------------------------------------------------------------------
__global__ __launch_bounds__(256) void gemm_k32_n64_act(
    const float* __restrict__ X, const float* __restrict__ W,
    const float* __restrict__ bias, float* __restrict__ out,
    uint32_t k0, uint32_t k1, int n) {
  __shared__ float Ws[32 * 64];
  __shared__ float Xs[16 * 36];
  int tid = threadIdx.x;
  {
    const float4* Wv = (const float4*)W;
    float4* Wsv = (float4*)Ws;
    Wsv[tid] = Wv[tid];
    Wsv[tid + 256] = Wv[tid + 256];
  }
  int row0 = blockIdx.x * 16;
  if (tid < 128) {
    const float4* Xv = (const float4*)(X + (size_t)row0 * 32);
    int lim = (n - row0) * 8;
    float4 z = make_float4(0.f, 0.f, 0.f, 0.f);
    float4 v = (tid < lim) ? Xv[tid] : z;
    *(float4*)(Xs + (tid >> 3) * 36 + ((tid & 7) << 2)) = v;
  }
  __syncthreads();
  int r = tid >> 4;
  int c4 = (tid & 15) << 2;
  int row = row0 + r;
  if (row >= n) return;
  float4 acc = make_float4(0.f, 0.f, 0.f, 0.f);
#pragma unroll
  for (int k = 0; k < 32; k += 4) {
    float4 xv = *(const float4*)(Xs + r * 36 + k);
    float4 w0 = *(const float4*)(Ws + (k + 0) * 64 + c4);
    float4 w1 = *(const float4*)(Ws + (k + 1) * 64 + c4);
    float4 w2 = *(const float4*)(Ws + (k + 2) * 64 + c4);
    float4 w3 = *(const float4*)(Ws + (k + 3) * 64 + c4);
    acc.x = fmaf(xv.x, w0.x, acc.x); acc.y = fmaf(xv.x, w0.y, acc.y);
    acc.z = fmaf(xv.x, w0.z, acc.z); acc.w = fmaf(xv.x, w0.w, acc.w);
    acc.x = fmaf(xv.y, w1.x, acc.x); acc.y = fmaf(xv.y, w1.y, acc.y);
    acc.z = fmaf(xv.y, w1.z, acc.z); acc.w = fmaf(xv.y, w1.w, acc.w);
    acc.x = fmaf(xv.z, w2.x, acc.x); acc.y = fmaf(xv.z, w2.y, acc.y);
    acc.z = fmaf(xv.z, w2.z, acc.z); acc.w = fmaf(xv.z, w2.w, acc.w);
    acc.x = fmaf(xv.w, w3.x, acc.x); acc.y = fmaf(xv.w, w3.y, acc.y);
    acc.z = fmaf(xv.w, w3.z, acc.z); acc.w = fmaf(xv.w, w3.w, acc.w);
  }
  float4 bv = *(const float4*)(bias + c4);
  float vv[4] = {acc.x + bv.x, acc.y + bv.y, acc.z + bv.z, acc.w + bv.w};
  uint32_t base = (uint32_t)row * 64u + (uint32_t)c4;
#pragma unroll
  for (int q = 0; q < 4; ++q) {
    float v = vv[q];
    v = v > 0.f ? v : expm1f(v);
    vv[q] = tf_keep(k0, k1, base + q) ? v * 2.f : 0.f;
  }
  *(float4*)(out + (size_t)row * 64 + c4) = make_float4(vv[0], vv[1], vv[2], vv[3]);
}

// ---------------------------------------------------------------------------
// Gather-reduce, fp16 table: 32 lanes per dst j; 64 B rows; one coalesced
// esrc load per 32-edge tile, src indices via shuffle; fp32 accumulation.
// mode 0 -> outf (fp32); mode 1 -> outf (fp32, final); mode 3 -> outh (fp16).
// ---------------------------------------------------------------------------
__global__ __launch_bounds__(256) void gather_fin(
    const half_t* __restrict__ hs, const uint32_t* __restrict__ rowp,
    const uint32_t* __restrict__ esrc, const float* __restrict__ dinv,
    const float* __restrict__ bias, float* __restrict__ outf,
    half_t* __restrict__ outh, int n, int mode, uint32_t k0, uint32_t k1) {
  int gt = blockIdx.x * 256 + threadIdx.x;
  int j = gt >> 5;
  if (j >= n) return;
  int l = threadIdx.x & 31;
  int eslot = l >> 3;
  int c4 = (l & 7) << 2;
  float4 acc = make_float4(0.f, 0.f, 0.f, 0.f);
  uint32_t e0 = rowp[j], e1 = rowp[j + 1];
  uint32_t deg = e1 - e0;
  uint32_t base = 0;
  for (; base + 32 <= deg; base += 32) {
    uint32_t idx = esrc[e0 + base + (uint32_t)l];
#pragma unroll
    for (int k = 0; k < 32; k += 4) {
      uint32_t s = (uint32_t)__shfl((int)idx, k + eslot, 32);
      const half4 v = *(const half4*)(hs + ((size_t)s << 5) + c4);
      acc.x += (float)v.x; acc.y += (float)v.y;
      acc.z += (float)v.z; acc.w += (float)v.w;
    }
  }
  if (base < deg) {
    uint32_t rem = deg - base;  // 1..31
    uint32_t li = (uint32_t)l < rem ? (uint32_t)l : rem - 1u;
    uint32_t idx = esrc[e0 + base + li];
    for (uint32_t k = 0; k < rem; k += 4) {
      uint32_t kk = k + (uint32_t)eslot;
      uint32_t ks = kk < rem ? kk : rem - 1u;
      uint32_t s = (uint32_t)__shfl((int)idx, (int)ks, 32);
      if (kk < rem) {
        const half4 v = *(const half4*)(hs + ((size_t)s << 5) + c4);
        acc.x += (float)v.x; acc.y += (float)v.y;
        acc.z += (float)v.z; acc.w += (float)v.w;
      }
    }
  }
  acc.x += __shfl_xor(acc.x, 8);  acc.y += __shfl_xor(acc.y, 8);
  acc.z += __shfl_xor(acc.z, 8);  acc.w += __shfl_xor(acc.w, 8);
  acc.x += __shfl_xor(acc.x, 16); acc.y += __shfl_xor(acc.y, 16);
  acc.z += __shfl_xor(acc.z, 16); acc.w += __shfl_xor(acc.w, 16);
  int srcLane = (threadIdx.x & 32) | (l >> 2);
  float va = __shfl(acc.x, srcLane);
  float vb = __shfl(acc.y, srcLane);
  float vc = __shfl(acc.z, srcLane);
  float vd = __shfl(acc.w, srcLane);
  float lo = (l & 1) ? vb : va;
  float hi = (l & 1) ? vd : vc;
  float sum = (l & 2) ? hi : lo;
  sum += (float)hs[gt];  // self-loop (already dinv[src]-scaled)
  float dj = dinv[j];
  float v = dj * sum;
  if (mode == 1) {
    v += bias[l];
    v = v > 0.f ? v : expm1f(v);
    outf[gt] = v;
  } else if (mode == 3) {
    v += bias[l];
    v = v > 0.f ? v : expm1f(v);
    v = tf_keep(k0, k1, (uint32_t)gt) ? v * 2.f : 0.f;
    v *= dj;
    outh[gt] = (half_t)v;
  } else {
    outf[gt] = v;
  }
}

// ---------------------------------------------------------------------------
extern "C" void kernel_launch(void* const* d_in, const int* in_sizes, int n_in,
                              void* d_out, int out_size, void* d_ws, size_t ws_size,
                              hipStream_t stream) {
  const float* x  = (const float*)d_in[0];
  const int*   ei = (const int*)d_in[1];
  const float* W1 = (const float*)d_in[2];
  const float* b1 = (const float*)d_in[3];
  const float* W2 = (const float*)d_in[4];
  const float* b2 = (const float*)d_in[5];
  const float* W3 = (const float*)d_in[6];
  const float* b3 = (const float*)d_in[7];
  float* out = (float*)d_out;

  const int n = in_sizes[0] / 64;
  const int E = in_sizes[1] / 2;
  const int* src = ei;
  const int* dst = ei + E;

  char* ws = (char*)d_ws;
  size_t off = 0;
  auto alloc = [&](size_t bytes) {
    void* p = ws + off;
    off = (off + bytes + 255) & ~(size_t)255;
    return p;
  };
  float*    A32   = (float*)alloc((size_t)n * 32 * 4);  // gather2 out / gemm2 in; aliased tbl
  float*    C     = (float*)alloc((size_t)n * 64 * 4);  // gemm2 out; aliased staging
  half_t*   A16   = (half_t*)alloc((size_t)n * 32 * 2); // gemm1/gemm3 out, gather1/3 in
  half_t*   B16   = (half_t*)alloc((size_t)n * 32 * 2); // gather1 out, gather2 in
  float*    dinv  = (float*)alloc((size_t)n * 4);
  uint32_t* rowp  = (uint32_t*)alloc((size_t)(n + 1) * 4);
  uint32_t* esrc  = (uint32_t*)alloc((size_t)E * 4);
  uint32_t* gbcnt = (uint32_t*)alloc(1024 * 4);
  uint32_t* bbase = (uint32_t*)alloc(1024 * 4);
  uint32_t* staging = (uint32_t*)C;    // C dead until layer 2
  uint32_t* tbl     = (uint32_t*)A32;  // A32 dead until gather2 (2.45MB <= 12.8MB)
  (void)ws_size; (void)n_in; (void)out_size;

  uint32_t k1a, k1b, k2a, k2b;
  tf2x32(0u, 42u, 0u, 0u, k1a, k1b);
  tf2x32(0u, 42u, 0u, 1u, k2a, k2b);

  const int NB   = (n + 127) >> 7;
  const int NBLK = (E + CHUNK - 1) / CHUNK;
  const int nv   = n * 32;
  const int gV   = (nv + 255) / 256;
  const int gG1  = (n + 31) / 32;
  const int gG2  = (n + 15) / 16;
  dim3 blk(256);

  // ---- CSR build ----
  zero1024<<<1, dim3(1024), 0, stream>>>(gbcnt);
  k4_binhist<<<NBLK, blk, 0, stream>>>(src, dst, tbl, gbcnt, staging, E, NB);
  k3_bscan<<<1, dim3(1024), 0, stream>>>(gbcnt, bbase, NB);
  k5_fin<<<NB, blk, 0, stream>>>(staging, tbl, bbase, rowp, dinv, esrc, n, E, NBLK, NB);

  // ---- layer 1: A16 = fp16(dinv*(x@W1)); gather -> B16 (fp16) ----
  gemm_n64_k32<<<gG1, blk, 0, stream>>>(x, W1, dinv, A16, n);
  gather_fin<<<gV, blk, 0, stream>>>(A16, rowp, esrc, dinv, b1, nullptr, B16, n, 3, k1a, k1b);

  // ---- layer 2: gather(B16) -> A32 (fp32); gemm2 -> C (fp32) ----
  gather_fin<<<gV, blk, 0, stream>>>(B16, rowp, esrc, dinv, nullptr, A32, nullptr, n, 0, 0u, 0u);
  gemm_k32_n64_act<<<gG2, blk, 0, stream>>>(A32, W2, b2, C, k2a, k2b, n);

  // ---- layer 3: A16 = fp16(dinv*(C@W3)); gather -> out (fp32) ----
  gemm_n64_k32<<<gG1, blk, 0, stream>>>(C, W3, dinv, A16, n);
  gather_fin<<<gV, blk, 0, stream>>>(A16, rowp, esrc, dinv, b3, out, nullptr, n, 1, 0u, 0u);
}